// Round 1
// baseline (441.581 us; speedup 1.0000x reference)
//
#include <hip/hip_runtime.h>
#include <math.h>

#define XD 8
#define UD 4
#define SDIM 2
#define HH 16
#define ITERS 12
#define SIGMAF 0.1f

__device__ inline float wave_min64(float v) {
#pragma unroll
    for (int off = 32; off >= 1; off >>= 1) v = fminf(v, __shfl_xor(v, off));
    return v;
}
__device__ inline float wave_sum64(float v) {
#pragma unroll
    for (int off = 32; off >= 1; off >>= 1) v += __shfl_xor(v, off);
    return v;
}

// Cooperative 8x8 inverse (SPD, no pivoting). 64 threads, lane (r,c).
// W is shared [8][16] scratch (augmented [src | I]).
__device__ void inv8(const float (*src)[8], float (*dst)[8], float (*W)[16],
                     int r, int c) {
    W[r][c]     = src[r][c];
    W[r][c + 8] = (r == c) ? 1.0f : 0.0f;
    __syncthreads();
#pragma unroll
    for (int k = 0; k < 8; ++k) {
        float pinv = 1.0f / W[k][k];
        float m    = W[r][k];      // pre-elimination value (row k lanes ignore)
        __syncthreads();
        if (r == k) { W[k][c] *= pinv; W[k][c + 8] *= pinv; }
        __syncthreads();
        float a0 = W[k][c], a1 = W[k][c + 8];
        if (r != k) { W[r][c] -= m * a0; W[r][c + 8] -= m * a1; }
        __syncthreads();
    }
    dst[r][c] = W[r][c + 8];
    __syncthreads();
}

extern "C" __global__ void __launch_bounds__(64)
mpc_ipm_kernel(const float* __restrict__ x0g, const float* __restrict__ fg,
               const float* __restrict__ Ag, const float* __restrict__ Bg,
               const float* __restrict__ Cg, const float* __restrict__ Qg,
               const float* __restrict__ Rg, float* __restrict__ out)
{
    const int bi  = blockIdx.x;
    const int tid = threadIdx.x;
    const int r = tid >> 3, c = tid & 7;   // 8x8 cell
    const int tu = tid >> 2, iu = tid & 3; // [16][4] cell

    __shared__ float Amat[8][8], Bmat[8][4], Cmat[8][2], Qmat[8][8], Rmat[4][4];
    __shared__ float Qi[8][8], Vv[8][8], Uu[8][8];     // Vv=A*Qi, Uu=A*Qi*A'
    __shared__ float W[8][16], W2[8][8];
    __shared__ float xs[16][8], us[16][4];
    __shared__ float s1[64], s2[64], l1[64], l2[64];
    __shared__ float nuv[17][8], dnu[17][8];           // [16] rows stay zero
    __shared__ float bv[16][8];
    __shared__ float rx[16][8], ru[64], rp[16][8];     // rhs1x, rhs1u, r_p
    __shared__ float ri1[64], ri2[64], rc1[64], rc2[64], dd1[64], dd2[64];
    __shared__ float Rti[16][16];                      // (R+diag)^-1 per t
    __shared__ float qx[16][8], qu[64];                // M^-1 rhs1
    __shared__ float gv[16][8], yv[16][8];
    __shared__ float Dt[16][8][8], Ci[16][8][8];       // S diag blocks / inverses
    __shared__ float hx[16][8], hu[64];
    __shared__ float dxv[16][8], duv[64];
    __shared__ float tv[8];

    // ---- load constant matrices ----
    Amat[r][c] = Ag[tid];
    Qmat[r][c] = Qg[tid];
    if (tid < 32) Bmat[tid >> 2][tid & 3] = Bg[tid];
    if (tid < 16) { Cmat[tid >> 1][tid & 1] = Cg[tid]; Rmat[tid >> 2][tid & 3] = Rg[tid]; }

    // ---- init IPM state: z=0, s=h=1, lam=1, nu=0 ----
    us[tu][iu] = 0.0f;
    s1[tid] = 1.0f; s2[tid] = 1.0f; l1[tid] = 1.0f; l2[tid] = 1.0f;
    for (int idx = tid; idx < 17 * 8; idx += 64) {
        nuv[idx >> 3][idx & 7] = 0.0f;
        dnu[idx >> 3][idx & 7] = 0.0f;
    }
    for (int idx = tid; idx < 128; idx += 64) xs[idx >> 3][idx & 7] = 0.0f;
    __syncthreads();

    // ---- b_t = C f_t (+ A x0 at t=0) ----
    const float* fptr = fg + bi * (HH * SDIM);
    const float* x0p  = x0g + bi * XD;
    for (int idx = tid; idx < 128; idx += 64) {
        int t = idx >> 3, i = idx & 7;
        float b = Cmat[i][0] * fptr[2 * t] + Cmat[i][1] * fptr[2 * t + 1];
        if (t == 0) {
#pragma unroll
            for (int j = 0; j < 8; ++j) b += Amat[i][j] * x0p[j];
        }
        bv[t][i] = b;
    }
    // ---- Qi = Q^-1, Vv = A Qi, Uu = Vv A' ----
    inv8(Qmat, Qi, W, r, c);
    {
        float a = 0.0f;
#pragma unroll
        for (int k = 0; k < 8; ++k) a += Amat[r][k] * Qi[k][c];
        Vv[r][c] = a;
    }
    __syncthreads();
    {
        float a = 0.0f;
#pragma unroll
        for (int k = 0; k < 8; ++k) a += Vv[r][k] * Amat[c][k];
        Uu[r][c] = a;
    }
    __syncthreads();

    // ================= IPM iterations =================
    for (int it = 0; it < ITERS; ++it) {
        // mu = mean(s*lam)
        float mu = wave_sum64(s1[tid] * l1[tid] + s2[tid] * l2[tid]) * (1.0f / 128.0f);

        // ---- Phase 1: residuals ----
        {   // u-block (one per lane)
            float uval = us[tu][iu];
            float rdu = 0.0f;
#pragma unroll
            for (int j = 0; j < 4; ++j) rdu += Rmat[iu][j] * us[tu][j];
            rdu += l1[tid] - l2[tid];
#pragma unroll
            for (int j = 0; j < 8; ++j) rdu -= Bmat[j][iu] * nuv[tu][j];
            float ri1v = uval + s1[tid] - 1.0f;
            float ri2v = -uval + s2[tid] - 1.0f;
            float rc1v = s1[tid] * l1[tid] - SIGMAF * mu;
            float rc2v = s2[tid] * l2[tid] - SIGMAF * mu;
            dd1[tid] = l1[tid] / s1[tid];
            dd2[tid] = l2[tid] / s2[tid];
            float w1 = (l1[tid] * ri1v - rc1v) / s1[tid];
            float w2 = (l2[tid] * ri2v - rc2v) / s2[tid];
            ru[tid]  = -(rdu + w1 - w2);
            ri1[tid] = ri1v; ri2[tid] = ri2v; rc1[tid] = rc1v; rc2[tid] = rc2v;
        }
        for (int idx = tid; idx < 128; idx += 64) {  // x-block (two per lane)
            int t = idx >> 3, i = idx & 7;
            float rdx = nuv[t][i];
#pragma unroll
            for (int j = 0; j < 8; ++j) rdx += Qmat[i][j] * xs[t][j];
#pragma unroll
            for (int j = 0; j < 8; ++j) rdx -= Amat[j][i] * nuv[t + 1][j];
            rx[t][i] = -rdx;
            float rpv = xs[t][i] - bv[t][i];
            if (t > 0) {
#pragma unroll
                for (int j = 0; j < 8; ++j) rpv -= Amat[i][j] * xs[t - 1][j];
            }
#pragma unroll
            for (int j = 0; j < 4; ++j) rpv -= Bmat[i][j] * us[t][j];
            rp[t][i] = rpv;
        }
        __syncthreads();

        // ---- Phase 2: Rti (16x 4x4 inverses, serial per lane) + qx ----
        if (tid < 16) {
            float Mx[4][4], Iv[4][4];
#pragma unroll
            for (int a = 0; a < 4; ++a)
#pragma unroll
                for (int b = 0; b < 4; ++b) { Mx[a][b] = Rmat[a][b]; Iv[a][b] = (a == b) ? 1.0f : 0.0f; }
#pragma unroll
            for (int a = 0; a < 4; ++a) Mx[a][a] += dd1[tid * 4 + a] + dd2[tid * 4 + a];
#pragma unroll
            for (int k = 0; k < 4; ++k) {
                float p = 1.0f / Mx[k][k];
#pragma unroll
                for (int b = 0; b < 4; ++b) { Mx[k][b] *= p; Iv[k][b] *= p; }
#pragma unroll
                for (int a = 0; a < 4; ++a) {
                    if (a == k) continue;
                    float m_ = Mx[a][k];
#pragma unroll
                    for (int b = 0; b < 4; ++b) { Mx[a][b] -= m_ * Mx[k][b]; Iv[a][b] -= m_ * Iv[k][b]; }
                }
            }
#pragma unroll
            for (int a = 0; a < 4; ++a)
#pragma unroll
                for (int b = 0; b < 4; ++b) Rti[tid][a * 4 + b] = Iv[a][b];
        }
        for (int idx = tid; idx < 128; idx += 64) {
            int t = idx >> 3, i = idx & 7;
            float a = 0.0f;
#pragma unroll
            for (int j = 0; j < 8; ++j) a += Qi[i][j] * rx[t][j];
            qx[t][i] = a;
        }
        __syncthreads();

        // ---- Phase 3: qu + Dt (S diag blocks) ----
        {
            float a = 0.0f;
#pragma unroll
            for (int j = 0; j < 4; ++j) a += Rti[tu][iu * 4 + j] * ru[tu * 4 + j];
            qu[tid] = a;
        }
        for (int t = 0; t < 16; ++t) {
            float a = Qi[r][c] + (t > 0 ? Uu[r][c] : 0.0f);
#pragma unroll
            for (int p = 0; p < 4; ++p) {
                float brp = Bmat[r][p];
#pragma unroll
                for (int q = 0; q < 4; ++q) a += brp * Rti[t][p * 4 + q] * Bmat[c][q];
            }
            Dt[t][r][c] = a;
        }
        __syncthreads();

        // ---- Phase 4: g = Am * q + r_p ----
        for (int idx = tid; idx < 128; idx += 64) {
            int t = idx >> 3, i = idx & 7;
            float a = qx[t][i] + rp[t][i];
            if (t > 0) {
#pragma unroll
                for (int j = 0; j < 8; ++j) a -= Amat[i][j] * qx[t - 1][j];
            }
#pragma unroll
            for (int j = 0; j < 4; ++j) a -= Bmat[i][j] * qu[t * 4 + j];
            gv[t][i] = a;
        }
        __syncthreads();

        // ---- Phase 5: block-tridiagonal forward sweep ----
        if (tid < 8) yv[0][tid] = gv[0][tid];
        inv8(Dt[0], Ci[0], W, r, c);
        for (int t = 1; t < 16; ++t) {
            {   // W2 = Vv * Ci[t-1]
                float a = 0.0f;
#pragma unroll
                for (int k = 0; k < 8; ++k) a += Vv[r][k] * Ci[t - 1][k][c];
                W2[r][c] = a;
            }
            __syncthreads();
            {   // Ct = Dt - W2 Vv' ; y_t = g_t + W2 y_{t-1}
                float b2 = Dt[t][r][c];
#pragma unroll
                for (int k = 0; k < 8; ++k) b2 -= W2[r][k] * Vv[c][k];
                Dt[t][r][c] = b2;
                if (c == 0) {
                    float yy = gv[t][r];
#pragma unroll
                    for (int k = 0; k < 8; ++k) yy += W2[r][k] * yv[t - 1][k];
                    yv[t][r] = yy;
                }
            }
            __syncthreads();
            inv8(Dt[t], Ci[t], W, r, c);
        }

        // ---- Phase 6: back substitution (dnu[16] == 0) ----
        for (int t = 15; t >= 0; --t) {
            if (tid < 8) {
                float a = yv[t][tid];
#pragma unroll
                for (int k = 0; k < 8; ++k) a += Vv[k][tid] * dnu[t + 1][k];
                tv[tid] = a;
            }
            __syncthreads();
            if (tid < 8) {
                float a = 0.0f;
#pragma unroll
                for (int k = 0; k < 8; ++k) a += Ci[t][tid][k] * tv[k];
                dnu[t][tid] = a;
            }
            __syncthreads();
        }

        // ---- Phase 7: dz = M^-1 (rhs1 - Am' dnu) ----
        for (int idx = tid; idx < 128; idx += 64) {
            int t = idx >> 3, i = idx & 7;
            float a = rx[t][i] - dnu[t][i];
#pragma unroll
            for (int k = 0; k < 8; ++k) a += Amat[k][i] * dnu[t + 1][k];
            hx[t][i] = a;
        }
        {
            float a = ru[tid];
#pragma unroll
            for (int k = 0; k < 8; ++k) a += Bmat[k][iu] * dnu[tu][k];
            hu[tid] = a;
        }
        __syncthreads();
        for (int idx = tid; idx < 128; idx += 64) {
            int t = idx >> 3, i = idx & 7;
            float a = 0.0f;
#pragma unroll
            for (int j = 0; j < 8; ++j) a += Qi[i][j] * hx[t][j];
            dxv[t][i] = a;
        }
        {
            float a = 0.0f;
#pragma unroll
            for (int j = 0; j < 4; ++j) a += Rti[tu][iu * 4 + j] * hu[tu * 4 + j];
            duv[tid] = a;
        }
        __syncthreads();

        // ---- Phase 8: ds, dlam, alpha, update ----
        float dss1 = -ri1[tid] - duv[tid];
        float dss2 = -ri2[tid] + duv[tid];
        float dll1 = (-rc1[tid] - l1[tid] * dss1) / s1[tid];
        float dll2 = (-rc2[tid] - l2[tid] * dss2) / s2[tid];
        float rmin = __builtin_inff();
        if (dss1 < 0.0f) rmin = fminf(rmin, -s1[tid] / dss1);
        if (dss2 < 0.0f) rmin = fminf(rmin, -s2[tid] / dss2);
        if (dll1 < 0.0f) rmin = fminf(rmin, -l1[tid] / dll1);
        if (dll2 < 0.0f) rmin = fminf(rmin, -l2[tid] / dll2);
        rmin = wave_min64(rmin);
        float alpha = fminf(1.0f, 0.99f * rmin);

        us[tu][iu] += alpha * duv[tid];
        s1[tid] += alpha * dss1; s2[tid] += alpha * dss2;
        l1[tid] += alpha * dll1; l2[tid] += alpha * dll2;
        for (int idx = tid; idx < 128; idx += 64) {
            int t = idx >> 3, i = idx & 7;
            xs[t][i]  += alpha * dxv[t][i];
            nuv[t][i] += alpha * dnu[t][i];
        }
        __syncthreads();
    }

    // ---- write outputs: x_sol (128,16,8) then u_sol (128,16,4) ----
    for (int idx = tid; idx < 128; idx += 64) {
        int t = idx >> 3, i = idx & 7;
        out[bi * 128 + t * 8 + i] = xs[t][i];
    }
    out[16384 + bi * 64 + tu * 4 + iu] = us[tu][iu];
}

extern "C" void kernel_launch(void* const* d_in, const int* in_sizes, int n_in,
                              void* d_out, int out_size, void* d_ws, size_t ws_size,
                              hipStream_t stream) {
    const float* x0 = (const float*)d_in[0];
    const float* fc = (const float*)d_in[1];
    const float* A  = (const float*)d_in[2];
    const float* B  = (const float*)d_in[3];
    const float* C  = (const float*)d_in[4];
    const float* Q  = (const float*)d_in[5];
    const float* R  = (const float*)d_in[6];
    float* out = (float*)d_out;
    const int batch = in_sizes[0] / XD;  // 128
    mpc_ipm_kernel<<<batch, 64, 0, stream>>>(x0, fc, A, B, C, Q, R, out);
}

// Round 2
// 222.518 us; speedup vs baseline: 1.9845x; 1.9845x over previous
//
#include <hip/hip_runtime.h>
#include <math.h>

#define XD 8
#define UD 4
#define SDIM 2
#define HH 16
#define ITERS 12
#define SIGMAF 0.1f

__device__ inline float wave_min64(float v) {
#pragma unroll
    for (int off = 32; off >= 1; off >>= 1) v = fminf(v, __shfl_xor(v, off));
    return v;
}
__device__ inline float wave_sum64(float v) {
#pragma unroll
    for (int off = 32; off >= 1; off >>= 1) v += __shfl_xor(v, off);
    return v;
}

// Cooperative 8x8 inverse via LDS (used once, for Q^-1 at setup).
__device__ void inv8_lds(const float (*src)[8], float (*dst)[8], float (*W)[16],
                         int r, int c) {
    W[r][c]     = src[r][c];
    W[r][c + 8] = (r == c) ? 1.0f : 0.0f;
    __syncthreads();
#pragma unroll
    for (int k = 0; k < 8; ++k) {
        float pinv = 1.0f / W[k][k];
        float m    = W[r][k];
        __syncthreads();
        if (r == k) { W[k][c] *= pinv; W[k][c + 8] *= pinv; }
        __syncthreads();
        float a0 = W[k][c], a1 = W[k][c + 8];
        if (r != k) { W[r][c] -= m * a0; W[r][c + 8] -= m * a1; }
        __syncthreads();
    }
    dst[r][c] = W[r][c + 8];
    __syncthreads();
}

// Register/shuffle 8x8 Gauss-Jordan inverse. Lane (r,c) holds element [r][c]
// of the input in w; returns inverse element [r][c]. Single wave, lockstep,
// no barriers: shuffles read pre-update values.
__device__ inline float inv8_reg(float w, int r, int c) {
    float ii = (r == c) ? 1.0f : 0.0f;
#pragma unroll
    for (int k = 0; k < 8; ++k) {
        float wkk = __shfl(w, k * 9);           // pivot W[k][k]
        float m   = __shfl(w, r * 8 + k);       // W[r][k] (pre-elim)
        float wkc = __shfl(w, k * 8 + c);       // row k of W
        float ikc = __shfl(ii, k * 8 + c);      // row k of I-part
        float pinv = __builtin_amdgcn_rcpf(wkk);
        float ws = wkc * pinv;
        float is_ = ikc * pinv;
        bool diag = (r == k);
        w  = diag ? ws  : (w  - m * ws);
        ii = diag ? is_ : (ii - m * is_);
    }
    return ii;
}

extern "C" __global__ void __launch_bounds__(64)
mpc_ipm_kernel(const float* __restrict__ x0g, const float* __restrict__ fg,
               const float* __restrict__ Ag, const float* __restrict__ Bg,
               const float* __restrict__ Cg, const float* __restrict__ Qg,
               const float* __restrict__ Rg, float* __restrict__ out)
{
    const int bi  = blockIdx.x;
    const int tid = threadIdx.x;
    const int r = tid >> 3, c = tid & 7;   // 8x8 cell
    const int tu = tid >> 2, iu = tid & 3; // [16][4] cell

    __shared__ float Amat[8][8], Bmat[8][4], Cmat[8][2], Qmat[8][8], Rmat[4][4];
    __shared__ float Qi[8][8], Vv[8][8], Uu[8][8];     // Vv=A*Qi, Uu=A*Qi*A'
    __shared__ float W[8][16];
    __shared__ float xs[16][8], us[16][4];
    __shared__ float s1[64], s2[64], l1[64], l2[64];
    __shared__ float nuv[17][8], dnu[17][8];           // row [16] stays zero
    __shared__ float bv[16][8];
    __shared__ float rx[16][8], ru[64], rp[16][8];
    __shared__ float ri1[64], ri2[64], rc1[64], rc2[64], dd1[64], dd2[64];
    __shared__ float Rti[16][16];                      // (R+diag)^-1 per t
    __shared__ float qx[16][8], qu[64];
    __shared__ float gv[16][8];
    __shared__ float hx[16][8], hu[64];
    __shared__ float dxv[16][8], duv[64];

    // ---- load constant matrices ----
    Amat[r][c] = Ag[tid];
    Qmat[r][c] = Qg[tid];
    if (tid < 32) Bmat[tid >> 2][tid & 3] = Bg[tid];
    if (tid < 16) { Cmat[tid >> 1][tid & 1] = Cg[tid]; Rmat[tid >> 2][tid & 3] = Rg[tid]; }

    // ---- init IPM state ----
    us[tu][iu] = 0.0f;
    s1[tid] = 1.0f; s2[tid] = 1.0f; l1[tid] = 1.0f; l2[tid] = 1.0f;
    for (int idx = tid; idx < 17 * 8; idx += 64) {
        nuv[idx >> 3][idx & 7] = 0.0f;
        dnu[idx >> 3][idx & 7] = 0.0f;
    }
    for (int idx = tid; idx < 128; idx += 64) xs[idx >> 3][idx & 7] = 0.0f;
    __syncthreads();

    // ---- b_t = C f_t (+ A x0 at t=0) ----
    const float* fptr = fg + bi * (HH * SDIM);
    const float* x0p  = x0g + bi * XD;
    for (int idx = tid; idx < 128; idx += 64) {
        int t = idx >> 3, i = idx & 7;
        float b = Cmat[i][0] * fptr[2 * t] + Cmat[i][1] * fptr[2 * t + 1];
        if (t == 0) {
#pragma unroll
            for (int j = 0; j < 8; ++j) b += Amat[i][j] * x0p[j];
        }
        bv[t][i] = b;
    }
    // ---- Qi = Q^-1, Vv = A Qi, Uu = Vv A' ----
    inv8_lds(Qmat, Qi, W, r, c);
    {
        float a = 0.0f;
#pragma unroll
        for (int k = 0; k < 8; ++k) a += Amat[r][k] * Qi[k][c];
        Vv[r][c] = a;
    }
    __syncthreads();
    {
        float a = 0.0f;
#pragma unroll
        for (int k = 0; k < 8; ++k) a += Vv[r][k] * Amat[c][k];
        Uu[r][c] = a;
    }
    __syncthreads();

    // ---- register-cache per-lane constants ----
    float vv = Vv[r][c];
    float qi_rc = Qi[r][c], uu_rc = Uu[r][c];
    float vvrow[8], vvcol[8];
#pragma unroll
    for (int k = 0; k < 8; ++k) { vvrow[k] = Vv[r][k]; vvcol[k] = Vv[c][k]; }
    float brow[4], bcol[4];
#pragma unroll
    for (int p = 0; p < 4; ++p) { brow[p] = Bmat[r][p]; bcol[p] = Bmat[c][p]; }

    // ================= IPM iterations =================
#pragma unroll 1
    for (int it = 0; it < ITERS; ++it) {
        float mu = wave_sum64(s1[tid] * l1[tid] + s2[tid] * l2[tid]) * (1.0f / 128.0f);

        // ---- Phase 1: residuals ----
        {
            float uval = us[tu][iu];
            float rdu = 0.0f;
#pragma unroll
            for (int j = 0; j < 4; ++j) rdu += Rmat[iu][j] * us[tu][j];
            rdu += l1[tid] - l2[tid];
#pragma unroll
            for (int j = 0; j < 8; ++j) rdu -= Bmat[j][iu] * nuv[tu][j];
            float ri1v = uval + s1[tid] - 1.0f;
            float ri2v = -uval + s2[tid] - 1.0f;
            float rc1v = s1[tid] * l1[tid] - SIGMAF * mu;
            float rc2v = s2[tid] * l2[tid] - SIGMAF * mu;
            dd1[tid] = l1[tid] / s1[tid];
            dd2[tid] = l2[tid] / s2[tid];
            float w1 = (l1[tid] * ri1v - rc1v) / s1[tid];
            float w2 = (l2[tid] * ri2v - rc2v) / s2[tid];
            ru[tid]  = -(rdu + w1 - w2);
            ri1[tid] = ri1v; ri2[tid] = ri2v; rc1[tid] = rc1v; rc2[tid] = rc2v;
        }
        for (int idx = tid; idx < 128; idx += 64) {
            int t = idx >> 3, i = idx & 7;
            float rdx = nuv[t][i];
#pragma unroll
            for (int j = 0; j < 8; ++j) rdx += Qmat[i][j] * xs[t][j];
#pragma unroll
            for (int j = 0; j < 8; ++j) rdx -= Amat[j][i] * nuv[t + 1][j];
            rx[t][i] = -rdx;
            float rpv = xs[t][i] - bv[t][i];
            if (t > 0) {
#pragma unroll
                for (int j = 0; j < 8; ++j) rpv -= Amat[i][j] * xs[t - 1][j];
            }
#pragma unroll
            for (int j = 0; j < 4; ++j) rpv -= Bmat[i][j] * us[t][j];
            rp[t][i] = rpv;
        }
        __syncthreads();

        // ---- Phase 2: Rti (16x 4x4 inverse, per-lane registers) + qx ----
        if (tid < 16) {
            float Mx[4][4], Iv[4][4];
#pragma unroll
            for (int a = 0; a < 4; ++a)
#pragma unroll
                for (int b = 0; b < 4; ++b) { Mx[a][b] = Rmat[a][b]; Iv[a][b] = (a == b) ? 1.0f : 0.0f; }
#pragma unroll
            for (int a = 0; a < 4; ++a) Mx[a][a] += dd1[tid * 4 + a] + dd2[tid * 4 + a];
#pragma unroll
            for (int k = 0; k < 4; ++k) {
                float p = __builtin_amdgcn_rcpf(Mx[k][k]);
#pragma unroll
                for (int b = 0; b < 4; ++b) { Mx[k][b] *= p; Iv[k][b] *= p; }
#pragma unroll
                for (int a = 0; a < 4; ++a) {
                    if (a == k) continue;
                    float m_ = Mx[a][k];
#pragma unroll
                    for (int b = 0; b < 4; ++b) { Mx[a][b] -= m_ * Mx[k][b]; Iv[a][b] -= m_ * Iv[k][b]; }
                }
            }
#pragma unroll
            for (int a = 0; a < 4; ++a)
#pragma unroll
                for (int b = 0; b < 4; ++b) Rti[tid][a * 4 + b] = Iv[a][b];
        }
        for (int idx = tid; idx < 128; idx += 64) {
            int t = idx >> 3, i = idx & 7;
            float a = 0.0f;
#pragma unroll
            for (int j = 0; j < 8; ++j) a += Qi[i][j] * rx[t][j];
            qx[t][i] = a;
        }
        __syncthreads();

        // ---- Phase 3: qu + Dt blocks (register array, per-lane element) ----
        {
            float a = 0.0f;
#pragma unroll
            for (int j = 0; j < 4; ++j) a += Rti[tu][iu * 4 + j] * ru[tu * 4 + j];
            qu[tid] = a;
        }
        float dt_all[16];
#pragma unroll
        for (int t = 0; t < 16; ++t) {
            float a = qi_rc + (t > 0 ? uu_rc : 0.0f);
#pragma unroll
            for (int p = 0; p < 4; ++p) {
                float brp = brow[p];
#pragma unroll
                for (int q = 0; q < 4; ++q) a += brp * Rti[t][p * 4 + q] * bcol[q];
            }
            dt_all[t] = a;
        }
        __syncthreads();

        // ---- Phase 4: g = Am * q + r_p ----
        for (int idx = tid; idx < 128; idx += 64) {
            int t = idx >> 3, i = idx & 7;
            float a = qx[t][i] + rp[t][i];
            if (t > 0) {
#pragma unroll
                for (int j = 0; j < 8; ++j) a -= Amat[i][j] * qx[t - 1][j];
            }
#pragma unroll
            for (int j = 0; j < 4; ++j) a -= Bmat[i][j] * qu[t * 4 + j];
            gv[t][i] = a;
        }
        __syncthreads();

        // ---- Phase 5: block-tridiagonal forward sweep (registers + shfl,
        //      zero barriers). Lane (r,c) owns element [r][c]. ----
        float ci_all[16], yall[16];
        float ci = inv8_reg(dt_all[0], r, c);
        ci_all[0] = ci;
        float ypc = gv[0][c];          // y_0[c], column-replicated
        yall[0] = ypc;
#pragma unroll
        for (int t = 1; t < 16; ++t) {
            // W2 = Vv * Ci[t-1]
            float w2 = 0.0f;
#pragma unroll
            for (int k = 0; k < 8; ++k) w2 += vvrow[k] * __shfl(ci, k * 8 + c);
            // Ct = Dt - W2 * Vv'
            float ct = dt_all[t];
#pragma unroll
            for (int k = 0; k < 8; ++k) ct -= __shfl(w2, r * 8 + k) * vvcol[k];
            // y_t = g_t + W2 * y_{t-1}   (row-sum within 8-lane rows)
            float pr = w2 * ypc;
            pr += __shfl_xor(pr, 1); pr += __shfl_xor(pr, 2); pr += __shfl_xor(pr, 4);
            float yrow = gv[t][r] + pr;            // row-replicated y_t[r]
            ypc = __shfl(yrow, c * 8);             // -> column-replicated
            yall[t] = ypc;
            ci = inv8_reg(ct, r, c);
            ci_all[t] = ci;
        }

        // ---- Phase 6: back substitution (registers + shfl) ----
        {
            float dn = 0.0f;                       // dnu[t+1][c], col-replicated
#pragma unroll
            for (int t = 15; t >= 0; --t) {
                float dnr = __shfl(dn, r);         // dnu[t+1][r]
                float p = vv * dnr;                // Vv[r][c]*dnu1[r]
                p += __shfl_xor(p, 8); p += __shfl_xor(p, 16); p += __shfl_xor(p, 32);
                float tvc = yall[t] + p;           // tv[c], col-replicated
                float p2 = ci_all[t] * tvc;        // Ci[t][r][c]*tv[c]
                p2 += __shfl_xor(p2, 1); p2 += __shfl_xor(p2, 2); p2 += __shfl_xor(p2, 4);
                if (c == 0) dnu[t][r] = p2;        // dnu_t[r]
                dn = __shfl(p2, c * 8);
            }
        }
        __syncthreads();

        // ---- Phase 7: dz = M^-1 (rhs1 - Am' dnu) ----
        for (int idx = tid; idx < 128; idx += 64) {
            int t = idx >> 3, i = idx & 7;
            float a = rx[t][i] - dnu[t][i];
#pragma unroll
            for (int k = 0; k < 8; ++k) a += Amat[k][i] * dnu[t + 1][k];
            hx[t][i] = a;
        }
        {
            float a = ru[tid];
#pragma unroll
            for (int k = 0; k < 8; ++k) a += Bmat[k][iu] * dnu[tu][k];
            hu[tid] = a;
        }
        __syncthreads();
        for (int idx = tid; idx < 128; idx += 64) {
            int t = idx >> 3, i = idx & 7;
            float a = 0.0f;
#pragma unroll
            for (int j = 0; j < 8; ++j) a += Qi[i][j] * hx[t][j];
            dxv[t][i] = a;
        }
        {
            float a = 0.0f;
#pragma unroll
            for (int j = 0; j < 4; ++j) a += Rti[tu][iu * 4 + j] * hu[tu * 4 + j];
            duv[tid] = a;
        }
        __syncthreads();

        // ---- Phase 8: ds, dlam, alpha, update ----
        float dss1 = -ri1[tid] - duv[tid];
        float dss2 = -ri2[tid] + duv[tid];
        float dll1 = (-rc1[tid] - l1[tid] * dss1) / s1[tid];
        float dll2 = (-rc2[tid] - l2[tid] * dss2) / s2[tid];
        float rmin = __builtin_inff();
        if (dss1 < 0.0f) rmin = fminf(rmin, -s1[tid] / dss1);
        if (dss2 < 0.0f) rmin = fminf(rmin, -s2[tid] / dss2);
        if (dll1 < 0.0f) rmin = fminf(rmin, -l1[tid] / dll1);
        if (dll2 < 0.0f) rmin = fminf(rmin, -l2[tid] / dll2);
        rmin = wave_min64(rmin);
        float alpha = fminf(1.0f, 0.99f * rmin);

        us[tu][iu] += alpha * duv[tid];
        s1[tid] += alpha * dss1; s2[tid] += alpha * dss2;
        l1[tid] += alpha * dll1; l2[tid] += alpha * dll2;
        for (int idx = tid; idx < 128; idx += 64) {
            int t = idx >> 3, i = idx & 7;
            xs[t][i]  += alpha * dxv[t][i];
            nuv[t][i] += alpha * dnu[t][i];
        }
        __syncthreads();
    }

    // ---- outputs: x_sol (128,16,8) then u_sol (128,16,4) ----
    for (int idx = tid; idx < 128; idx += 64) {
        int t = idx >> 3, i = idx & 7;
        out[bi * 128 + t * 8 + i] = xs[t][i];
    }
    out[16384 + bi * 64 + tu * 4 + iu] = us[tu][iu];
}

extern "C" void kernel_launch(void* const* d_in, const int* in_sizes, int n_in,
                              void* d_out, int out_size, void* d_ws, size_t ws_size,
                              hipStream_t stream) {
    const float* x0 = (const float*)d_in[0];
    const float* fc = (const float*)d_in[1];
    const float* A  = (const float*)d_in[2];
    const float* B  = (const float*)d_in[3];
    const float* C  = (const float*)d_in[4];
    const float* Q  = (const float*)d_in[5];
    const float* R  = (const float*)d_in[6];
    float* out = (float*)d_out;
    const int batch = in_sizes[0] / XD;  // 128
    mpc_ipm_kernel<<<batch, 64, 0, stream>>>(x0, fc, A, B, C, Q, R, out);
}

// Round 4
// 197.650 us; speedup vs baseline: 2.2341x; 1.1258x over previous
//
#include <hip/hip_runtime.h>
#include <math.h>

#define XD 8
#define UD 4
#define SDIM 2
#define HH 16
#define ITERS 12
#define SIGMAF 0.1f

__device__ inline float wave_min64(float v) {
#pragma unroll
    for (int off = 32; off >= 1; off >>= 1) v = fminf(v, __shfl_xor(v, off));
    return v;
}
__device__ inline float wave_sum64(float v) {
#pragma unroll
    for (int off = 32; off >= 1; off >>= 1) v += __shfl_xor(v, off);
    return v;
}

// Cooperative 8x8 inverse via LDS (used once, for Q^-1 at setup).
__device__ void inv8_lds(const float (*src)[8], float (*dst)[8], float (*W)[16],
                         int r, int c) {
    W[r][c]     = src[r][c];
    W[r][c + 8] = (r == c) ? 1.0f : 0.0f;
    __syncthreads();
#pragma unroll
    for (int k = 0; k < 8; ++k) {
        float pinv = 1.0f / W[k][k];
        float m    = W[r][k];
        __syncthreads();
        if (r == k) { W[k][c] *= pinv; W[k][c + 8] *= pinv; }
        __syncthreads();
        float a0 = W[k][c], a1 = W[k][c + 8];
        if (r != k) { W[r][c] -= m * a0; W[r][c + 8] -= m * a1; }
        __syncthreads();
    }
    dst[r][c] = W[r][c + 8];
    __syncthreads();
}

// Register/shuffle 8x8 Gauss-Jordan inverse (single matrix).
__device__ inline float inv8_reg(float w, int r, int c) {
    float ii = (r == c) ? 1.0f : 0.0f;
#pragma unroll
    for (int k = 0; k < 8; ++k) {
        float wkk = __shfl(w, k * 9);
        float m   = __shfl(w, r * 8 + k);
        float wkc = __shfl(w, k * 8 + c);
        float ikc = __shfl(ii, k * 8 + c);
        float pinv = __builtin_amdgcn_rcpf(wkk);
        float ws = wkc * pinv;
        float is_ = ikc * pinv;
        bool diag = (r == k);
        w  = diag ? ws  : (w  - m * ws);
        ii = diag ? is_ : (ii - m * is_);
    }
    return ii;
}

// Dual interleaved 8x8 Gauss-Jordan inverse: two independent chains (ILP).
__device__ inline void inv8_reg2(float wa, float wb, int r, int c,
                                 float& ia_out, float& ib_out) {
    float ia = (r == c) ? 1.0f : 0.0f;
    float ib = ia;
#pragma unroll
    for (int k = 0; k < 8; ++k) {
        float akk = __shfl(wa, k * 9);
        float bkk = __shfl(wb, k * 9);
        float ma  = __shfl(wa, r * 8 + k);
        float mb  = __shfl(wb, r * 8 + k);
        float akc = __shfl(wa, k * 8 + c);
        float bkc = __shfl(wb, k * 8 + c);
        float aic = __shfl(ia, k * 8 + c);
        float bic = __shfl(ib, k * 8 + c);
        float pa = __builtin_amdgcn_rcpf(akk);
        float pb = __builtin_amdgcn_rcpf(bkk);
        float was = akc * pa, wbs = bkc * pb;
        float ias = aic * pa, ibs = bic * pb;
        bool diag = (r == k);
        wa = diag ? was : (wa - ma * was);
        ia = diag ? ias : (ia - ma * ias);
        wb = diag ? wbs : (wb - mb * wbs);
        ib = diag ? ibs : (ib - mb * ibs);
    }
    ia_out = ia; ib_out = ib;
}

extern "C" __global__ void __launch_bounds__(64)
mpc_ipm_kernel(const float* __restrict__ x0g, const float* __restrict__ fg,
               const float* __restrict__ Ag, const float* __restrict__ Bg,
               const float* __restrict__ Cg, const float* __restrict__ Qg,
               const float* __restrict__ Rg, float* __restrict__ out)
{
    const int bi  = blockIdx.x;
    const int tid = threadIdx.x;
    const int r = tid >> 3, c = tid & 7;   // 8x8 cell
    const int tu = tid >> 2, iu = tid & 3; // [16][4] cell

    __shared__ float Amat[8][8], Bmat[8][4], Cmat[8][2], Qmat[8][8], Rmat[4][4];
    __shared__ float Qi[8][8], Vv[8][8], Uu[8][8];     // Vv=A*Qi, Uu=A*Qi*A'
    __shared__ float W[8][16];
    __shared__ float xs[16][8], us[16][4];
    __shared__ float s1[64], s2[64], l1[64], l2[64];
    __shared__ float nuv[17][8], dnu[17][8];           // row [16] stays zero
    __shared__ float bv[16][8];
    __shared__ float rx[16][8], ru[64], rp[16][8];
    __shared__ float ri1[64], ri2[64], rc1[64], rc2[64], dd1[64], dd2[64];
    __shared__ float Rti[16][16];                      // (R+diag)^-1 per t
    __shared__ float qx[16][8], qu[64];
    __shared__ float gv[16][8];
    __shared__ float hx[16][8], hu[64];
    __shared__ float dxv[16][8], duv[64];

    // ---- load constant matrices ----
    Amat[r][c] = Ag[tid];
    Qmat[r][c] = Qg[tid];
    if (tid < 32) Bmat[tid >> 2][tid & 3] = Bg[tid];
    if (tid < 16) { Cmat[tid >> 1][tid & 1] = Cg[tid]; Rmat[tid >> 2][tid & 3] = Rg[tid]; }

    // ---- init IPM state ----
    us[tu][iu] = 0.0f;
    s1[tid] = 1.0f; s2[tid] = 1.0f; l1[tid] = 1.0f; l2[tid] = 1.0f;
    for (int idx = tid; idx < 17 * 8; idx += 64) {
        nuv[idx >> 3][idx & 7] = 0.0f;
        dnu[idx >> 3][idx & 7] = 0.0f;
    }
    for (int idx = tid; idx < 128; idx += 64) xs[idx >> 3][idx & 7] = 0.0f;
    __syncthreads();

    // ---- b_t = C f_t (+ A x0 at t=0) ----
    const float* fptr = fg + bi * (HH * SDIM);
    const float* x0p  = x0g + bi * XD;
    for (int idx = tid; idx < 128; idx += 64) {
        int t = idx >> 3, i = idx & 7;
        float b = Cmat[i][0] * fptr[2 * t] + Cmat[i][1] * fptr[2 * t + 1];
        if (t == 0) {
#pragma unroll
            for (int j = 0; j < 8; ++j) b += Amat[i][j] * x0p[j];
        }
        bv[t][i] = b;
    }
    // ---- Qi = Q^-1, Vv = A Qi, Uu = Vv A' ----
    inv8_lds(Qmat, Qi, W, r, c);
    {
        float a = 0.0f;
#pragma unroll
        for (int k = 0; k < 8; ++k) a += Amat[r][k] * Qi[k][c];
        Vv[r][c] = a;
    }
    __syncthreads();
    {
        float a = 0.0f;
#pragma unroll
        for (int k = 0; k < 8; ++k) a += Vv[r][k] * Amat[c][k];
        Uu[r][c] = a;
    }
    __syncthreads();

    // ---- register-cache per-lane constants ----
    float vv = Vv[r][c];
    float vv_cr = Vv[c][r];
    float qi_rc = Qi[r][c], uu_rc = Uu[r][c];
    float vvrow[8], vvcol[8], vTrow[8], vTcol[8];
#pragma unroll
    for (int k = 0; k < 8; ++k) {
        vvrow[k] = Vv[r][k]; vvcol[k] = Vv[c][k];
        vTrow[k] = Vv[k][r]; vTcol[k] = Vv[k][c];
    }
    float brow[4], bcol[4];
#pragma unroll
    for (int p = 0; p < 4; ++p) { brow[p] = Bmat[r][p]; bcol[p] = Bmat[c][p]; }

    // ================= IPM iterations =================
#pragma unroll 1
    for (int it = 0; it < ITERS; ++it) {
        float mu = wave_sum64(s1[tid] * l1[tid] + s2[tid] * l2[tid]) * (1.0f / 128.0f);

        // ---- Phase 1: residuals ----
        {
            float uval = us[tu][iu];
            float rdu = 0.0f;
#pragma unroll
            for (int j = 0; j < 4; ++j) rdu += Rmat[iu][j] * us[tu][j];
            rdu += l1[tid] - l2[tid];
#pragma unroll
            for (int j = 0; j < 8; ++j) rdu -= Bmat[j][iu] * nuv[tu][j];
            float ri1v = uval + s1[tid] - 1.0f;
            float ri2v = -uval + s2[tid] - 1.0f;
            float rc1v = s1[tid] * l1[tid] - SIGMAF * mu;
            float rc2v = s2[tid] * l2[tid] - SIGMAF * mu;
            dd1[tid] = l1[tid] / s1[tid];
            dd2[tid] = l2[tid] / s2[tid];
            float w1 = (l1[tid] * ri1v - rc1v) / s1[tid];
            float w2 = (l2[tid] * ri2v - rc2v) / s2[tid];
            ru[tid]  = -(rdu + w1 - w2);
            ri1[tid] = ri1v; ri2[tid] = ri2v; rc1[tid] = rc1v; rc2[tid] = rc2v;
        }
        for (int idx = tid; idx < 128; idx += 64) {
            int t = idx >> 3, i = idx & 7;
            float rdx = nuv[t][i];
#pragma unroll
            for (int j = 0; j < 8; ++j) rdx += Qmat[i][j] * xs[t][j];
#pragma unroll
            for (int j = 0; j < 8; ++j) rdx -= Amat[j][i] * nuv[t + 1][j];
            rx[t][i] = -rdx;
            float rpv = xs[t][i] - bv[t][i];
            if (t > 0) {
#pragma unroll
                for (int j = 0; j < 8; ++j) rpv -= Amat[i][j] * xs[t - 1][j];
            }
#pragma unroll
            for (int j = 0; j < 4; ++j) rpv -= Bmat[i][j] * us[t][j];
            rp[t][i] = rpv;
        }
        __syncthreads();

        // ---- Phase 2: Rti (16x 4x4 inverse, per-lane registers) + qx ----
        if (tid < 16) {
            float Mx[4][4], Iv[4][4];
#pragma unroll
            for (int a = 0; a < 4; ++a)
#pragma unroll
                for (int b = 0; b < 4; ++b) { Mx[a][b] = Rmat[a][b]; Iv[a][b] = (a == b) ? 1.0f : 0.0f; }
#pragma unroll
            for (int a = 0; a < 4; ++a) Mx[a][a] += dd1[tid * 4 + a] + dd2[tid * 4 + a];
#pragma unroll
            for (int k = 0; k < 4; ++k) {
                float p = __builtin_amdgcn_rcpf(Mx[k][k]);
#pragma unroll
                for (int b = 0; b < 4; ++b) { Mx[k][b] *= p; Iv[k][b] *= p; }
#pragma unroll
                for (int a = 0; a < 4; ++a) {
                    if (a == k) continue;
                    float m_ = Mx[a][k];
#pragma unroll
                    for (int b = 0; b < 4; ++b) { Mx[a][b] -= m_ * Mx[k][b]; Iv[a][b] -= m_ * Iv[k][b]; }
                }
            }
#pragma unroll
            for (int a = 0; a < 4; ++a)
#pragma unroll
                for (int b = 0; b < 4; ++b) Rti[tid][a * 4 + b] = Iv[a][b];
        }
        for (int idx = tid; idx < 128; idx += 64) {
            int t = idx >> 3, i = idx & 7;
            float a = 0.0f;
#pragma unroll
            for (int j = 0; j < 8; ++j) a += Qi[i][j] * rx[t][j];
            qx[t][i] = a;
        }
        __syncthreads();

        // ---- Phase 3: qu + Dt blocks (register array, per-lane element) ----
        {
            float a = 0.0f;
#pragma unroll
            for (int j = 0; j < 4; ++j) a += Rti[tu][iu * 4 + j] * ru[tu * 4 + j];
            qu[tid] = a;
        }
        float dt_all[16];
#pragma unroll
        for (int t = 0; t < 16; ++t) {
            float a = qi_rc + (t > 0 ? uu_rc : 0.0f);
#pragma unroll
            for (int p = 0; p < 4; ++p) {
                float brp = brow[p];
#pragma unroll
                for (int q = 0; q < 4; ++q) a += brp * Rti[t][p * 4 + q] * bcol[q];
            }
            dt_all[t] = a;
        }
        __syncthreads();

        // ---- Phase 4: g = Am * q + r_p ----
        for (int idx = tid; idx < 128; idx += 64) {
            int t = idx >> 3, i = idx & 7;
            float a = qx[t][i] + rp[t][i];
            if (t > 0) {
#pragma unroll
                for (int j = 0; j < 8; ++j) a -= Amat[i][j] * qx[t - 1][j];
            }
#pragma unroll
            for (int j = 0; j < 4; ++j) a -= Bmat[i][j] * qu[t * 4 + j];
            gv[t][i] = a;
        }
        __syncthreads();

        // ---- Phase 5: DUAL-ENDED block-tridiagonal elimination.
        //      Forward chain t=0..7, backward chain t=15..8 — two independent
        //      dependency chains interleaved for ILP. Zero barriers. ----
        float cif_all[8], cib_all[7], yfall[8], yball[7];
        float cif, cib;
        inv8_reg2(dt_all[0], dt_all[15], r, c, cif, cib);
        cif_all[0] = cif; cib_all[0] = cib;
        float ypf = gv[0][c];            // y-fwd, col-replicated
        float ypb = gv[15][c];           // y-bwd, col-replicated
        yfall[0] = ypf; yball[0] = ypb;
#pragma unroll
        for (int s = 1; s < 7; ++s) {
            // forward combine at t=s ; backward combine at t=15-s
            float w2f = 0.0f, w2b = 0.0f;
#pragma unroll
            for (int k = 0; k < 8; ++k) w2f += vvrow[k] * __shfl(cif, k * 8 + c);
#pragma unroll
            for (int k = 0; k < 8; ++k) w2b += vTrow[k] * __shfl(cib, k * 8 + c);
            float ctf = dt_all[s], ctb = dt_all[15 - s];
#pragma unroll
            for (int k = 0; k < 8; ++k) ctf -= __shfl(w2f, r * 8 + k) * vvcol[k];
#pragma unroll
            for (int k = 0; k < 8; ++k) ctb -= __shfl(w2b, r * 8 + k) * vTcol[k];
            float prf = w2f * ypf, prb = w2b * ypb;
            prf += __shfl_xor(prf, 1); prf += __shfl_xor(prf, 2); prf += __shfl_xor(prf, 4);
            prb += __shfl_xor(prb, 1); prb += __shfl_xor(prb, 2); prb += __shfl_xor(prb, 4);
            float yfrow = gv[s][r] + prf;
            float ybrow = gv[15 - s][r] + prb;
            ypf = __shfl(yfrow, c * 8);
            ypb = __shfl(ybrow, c * 8);
            yfall[s] = ypf; yball[s] = ypb;
            inv8_reg2(ctf, ctb, r, c, cif, cib);
            cif_all[s] = cif; cib_all[s] = cib;
        }
        // ---- junction: forward combine t=7; backward combine t=8 (no invert);
        //      K = C~8 - V Cf7^-1 V' ; x8 = K^-1 (y~8 + V Cf7^-1 y^7) ----
        float x8col;
        {
            float w2f = 0.0f, w2b = 0.0f;
#pragma unroll
            for (int k = 0; k < 8; ++k) w2f += vvrow[k] * __shfl(cif, k * 8 + c);
#pragma unroll
            for (int k = 0; k < 8; ++k) w2b += vTrow[k] * __shfl(cib, k * 8 + c);
            float ctf = dt_all[7], ctb8 = dt_all[8];
#pragma unroll
            for (int k = 0; k < 8; ++k) ctf -= __shfl(w2f, r * 8 + k) * vvcol[k];
#pragma unroll
            for (int k = 0; k < 8; ++k) ctb8 -= __shfl(w2b, r * 8 + k) * vTcol[k];
            float prf = w2f * ypf, prb = w2b * ypb;
            prf += __shfl_xor(prf, 1); prf += __shfl_xor(prf, 2); prf += __shfl_xor(prf, 4);
            prb += __shfl_xor(prb, 1); prb += __shfl_xor(prb, 2); prb += __shfl_xor(prb, 4);
            float yfrow = gv[7][r] + prf;
            float ybrow8 = gv[8][r] + prb;           // y~8, row-replicated
            ypf = __shfl(yfrow, c * 8);
            yfall[7] = ypf;
            cif = inv8_reg(ctf, r, c);               // Cf7^-1
            cif_all[7] = cif;
            // K combine (forward-style step applied to backward diag)
            float w2K = 0.0f;
#pragma unroll
            for (int k = 0; k < 8; ++k) w2K += vvrow[k] * __shfl(cif, k * 8 + c);
            float Kel = ctb8;
#pragma unroll
            for (int k = 0; k < 8; ++k) Kel -= __shfl(w2K, r * 8 + k) * vvcol[k];
            float prK = w2K * ypf;                   // V Cf7^-1 y^7
            prK += __shfl_xor(prK, 1); prK += __shfl_xor(prK, 2); prK += __shfl_xor(prK, 4);
            float yKrow = ybrow8 + prK;
            float kinv = inv8_reg(Kel, r, c);
            float yKcol = __shfl(yKrow, c * 8);
            float p2 = kinv * yKcol;
            p2 += __shfl_xor(p2, 1); p2 += __shfl_xor(p2, 2); p2 += __shfl_xor(p2, 4);
            if (c == 0) dnu[8][r] = p2;              // x8, row-replicated
            x8col = __shfl(p2, c * 8);
        }
        // ---- Phase 6: dual outward back-substitution ----
        {
            float xlo = x8col, xhi = x8col;
#pragma unroll
            for (int j = 0; j < 8; ++j) {
                // lower: t = 7-j : x_t = Cf_t^-1 (y^_t + V' x_{t+1})
                float dnr = __shfl(xlo, r);
                float p = vv * dnr;
                p += __shfl_xor(p, 8); p += __shfl_xor(p, 16); p += __shfl_xor(p, 32);
                float tvc = yfall[7 - j] + p;
                float p2l = cif_all[7 - j] * tvc;
                p2l += __shfl_xor(p2l, 1); p2l += __shfl_xor(p2l, 2); p2l += __shfl_xor(p2l, 4);
                if (c == 0) dnu[7 - j][r] = p2l;
                xlo = __shfl(p2l, c * 8);
                // upper: t = 9+j : x_t = C~_t^-1 (y~_t + V x_{t-1})
                if (j < 7) {
                    float xr = __shfl(xhi, r);
                    float pu = vv_cr * xr;
                    pu += __shfl_xor(pu, 8); pu += __shfl_xor(pu, 16); pu += __shfl_xor(pu, 32);
                    float tvcu = yball[6 - j] + pu;
                    float p2u = cib_all[6 - j] * tvcu;
                    p2u += __shfl_xor(p2u, 1); p2u += __shfl_xor(p2u, 2); p2u += __shfl_xor(p2u, 4);
                    if (c == 0) dnu[9 + j][r] = p2u;
                    xhi = __shfl(p2u, c * 8);
                }
            }
        }
        __syncthreads();

        // ---- Phase 7: dz = M^-1 (rhs1 - Am' dnu) ----
        for (int idx = tid; idx < 128; idx += 64) {
            int t = idx >> 3, i = idx & 7;
            float a = rx[t][i] - dnu[t][i];
#pragma unroll
            for (int k = 0; k < 8; ++k) a += Amat[k][i] * dnu[t + 1][k];
            hx[t][i] = a;
        }
        {
            float a = ru[tid];
#pragma unroll
            for (int k = 0; k < 8; ++k) a += Bmat[k][iu] * dnu[tu][k];
            hu[tid] = a;
        }
        __syncthreads();
        for (int idx = tid; idx < 128; idx += 64) {
            int t = idx >> 3, i = idx & 7;
            float a = 0.0f;
#pragma unroll
            for (int j = 0; j < 8; ++j) a += Qi[i][j] * hx[t][j];
            dxv[t][i] = a;
        }
        {
            float a = 0.0f;
#pragma unroll
            for (int j = 0; j < 4; ++j) a += Rti[tu][iu * 4 + j] * hu[tu * 4 + j];
            duv[tid] = a;
        }
        __syncthreads();

        // ---- Phase 8: ds, dlam, alpha, update ----
        float dss1 = -ri1[tid] - duv[tid];
        float dss2 = -ri2[tid] + duv[tid];
        float dll1 = (-rc1[tid] - l1[tid] * dss1) / s1[tid];
        float dll2 = (-rc2[tid] - l2[tid] * dss2) / s2[tid];
        float rmin = __builtin_inff();
        if (dss1 < 0.0f) rmin = fminf(rmin, -s1[tid] / dss1);
        if (dss2 < 0.0f) rmin = fminf(rmin, -s2[tid] / dss2);
        if (dll1 < 0.0f) rmin = fminf(rmin, -l1[tid] / dll1);
        if (dll2 < 0.0f) rmin = fminf(rmin, -l2[tid] / dll2);
        rmin = wave_min64(rmin);
        float alpha = fminf(1.0f, 0.99f * rmin);

        us[tu][iu] += alpha * duv[tid];
        s1[tid] += alpha * dss1; s2[tid] += alpha * dss2;
        l1[tid] += alpha * dll1; l2[tid] += alpha * dll2;
        for (int idx = tid; idx < 128; idx += 64) {
            int t = idx >> 3, i = idx & 7;
            xs[t][i]  += alpha * dxv[t][i];
            nuv[t][i] += alpha * dnu[t][i];
        }
        __syncthreads();
    }

    // ---- outputs: x_sol (128,16,8) then u_sol (128,16,4) ----
    for (int idx = tid; idx < 128; idx += 64) {
        int t = idx >> 3, i = idx & 7;
        out[bi * 128 + t * 8 + i] = xs[t][i];
    }
    out[16384 + bi * 64 + tu * 4 + iu] = us[tu][iu];
}

extern "C" void kernel_launch(void* const* d_in, const int* in_sizes, int n_in,
                              void* d_out, int out_size, void* d_ws, size_t ws_size,
                              hipStream_t stream) {
    const float* x0 = (const float*)d_in[0];
    const float* fc = (const float*)d_in[1];
    const float* A  = (const float*)d_in[2];
    const float* B  = (const float*)d_in[3];
    const float* C  = (const float*)d_in[4];
    const float* Q  = (const float*)d_in[5];
    const float* R  = (const float*)d_in[6];
    float* out = (float*)d_out;
    const int batch = in_sizes[0] / XD;  // 128
    mpc_ipm_kernel<<<batch, 64, 0, stream>>>(x0, fc, A, B, C, Q, R, out);
}

// Round 5
// 178.965 us; speedup vs baseline: 2.4674x; 1.1044x over previous
//
#include <hip/hip_runtime.h>
#include <math.h>

#define ITERS 12
#define SIGMAF 0.1f

__device__ inline float wave_min64(float v) {
#pragma unroll
    for (int off = 32; off >= 1; off >>= 1) v = fminf(v, __shfl_xor(v, off));
    return v;
}
__device__ inline float wave_sum64(float v) {
#pragma unroll
    for (int off = 32; off >= 1; off >>= 1) v += __shfl_xor(v, off);
    return v;
}

// Cooperative 8x8 inverse via LDS (setup only).
__device__ void inv8_lds(const float (*src)[8], float (*dst)[8], float (*W)[16],
                         int r, int c) {
    W[r][c]     = src[r][c];
    W[r][c + 8] = (r == c) ? 1.0f : 0.0f;
    __syncthreads();
#pragma unroll
    for (int k = 0; k < 8; ++k) {
        float pinv = 1.0f / W[k][k];
        float m    = W[r][k];
        __syncthreads();
        if (r == k) { W[k][c] *= pinv; W[k][c + 8] *= pinv; }
        __syncthreads();
        float a0 = W[k][c], a1 = W[k][c + 8];
        if (r != k) { W[r][c] -= m * a0; W[r][c + 8] -= m * a1; }
        __syncthreads();
    }
    dst[r][c] = W[r][c + 8];
    __syncthreads();
}

// Register/shuffle 8x8 Gauss-Jordan inverse (single matrix).
__device__ inline float inv8_reg(float w, int r, int c) {
    float ii = (r == c) ? 1.0f : 0.0f;
#pragma unroll
    for (int k = 0; k < 8; ++k) {
        float wkk = __shfl(w, k * 9);
        float m   = __shfl(w, r * 8 + k);
        float wkc = __shfl(w, k * 8 + c);
        float ikc = __shfl(ii, k * 8 + c);
        float pinv = __builtin_amdgcn_rcpf(wkk);
        float ws = wkc * pinv;
        float is_ = ikc * pinv;
        bool diag = (r == k);
        w  = diag ? ws  : (w  - m * ws);
        ii = diag ? is_ : (ii - m * is_);
    }
    return ii;
}

// Dual interleaved 8x8 GJ inverse: two independent chains (ILP).
__device__ inline void inv8_reg2(float wa, float wb, int r, int c,
                                 float& ia_out, float& ib_out) {
    float ia = (r == c) ? 1.0f : 0.0f;
    float ib = ia;
#pragma unroll
    for (int k = 0; k < 8; ++k) {
        float akk = __shfl(wa, k * 9);
        float bkk = __shfl(wb, k * 9);
        float ma  = __shfl(wa, r * 8 + k);
        float mb  = __shfl(wb, r * 8 + k);
        float akc = __shfl(wa, k * 8 + c);
        float bkc = __shfl(wb, k * 8 + c);
        float aic = __shfl(ia, k * 8 + c);
        float bic = __shfl(ib, k * 8 + c);
        float pa = __builtin_amdgcn_rcpf(akk);
        float pb = __builtin_amdgcn_rcpf(bkk);
        float was = akc * pa, wbs = bkc * pb;
        float ias = aic * pa, ibs = bic * pb;
        bool diag = (r == k);
        wa = diag ? was : (wa - ma * was);
        ia = diag ? ias : (ia - ma * ias);
        wb = diag ? wbs : (wb - mb * wbs);
        ib = diag ? ibs : (ib - mb * ibs);
    }
    ia_out = ia; ib_out = ib;
}

extern "C" __global__ void __launch_bounds__(64)
mpc_ipm_kernel(const float* __restrict__ x0g, const float* __restrict__ fg,
               const float* __restrict__ Ag, const float* __restrict__ Bg,
               const float* __restrict__ Cg, const float* __restrict__ Qg,
               const float* __restrict__ Rg, float* __restrict__ out)
{
    const int bi  = blockIdx.x;
    const int tid = threadIdx.x;
    const int g = tid >> 3, i = tid & 7;     // lane (g,i); also (r,c) in P3/5/6
    const int isel = i & 4;                  // u-half selector (0 or 4)
    const int pu = i & 3;
    const int g8 = g * 8;
    const int gp1 = ((g + 1) & 7) * 8, gm1 = ((g - 1) & 7) * 8;

    __shared__ float Amat[8][8], Bmat[8][4], Cmat[8][2], Qmat[8][8], Rmat[4][4];
    __shared__ float Qi[8][8], Vv[8][8], Uu[8][8];
    __shared__ float W[8][16];
    __shared__ float Rti[16][16];
    float* rti_f = &Rti[0][0];

    // ---- load constant matrices ----
    Amat[g][i] = Ag[tid];
    Qmat[g][i] = Qg[tid];
    if (tid < 32) Bmat[tid >> 2][tid & 3] = Bg[tid];
    if (tid < 16) { Cmat[tid >> 1][tid & 1] = Cg[tid]; Rmat[tid >> 2][tid & 3] = Rg[tid]; }
    __syncthreads();

    // ---- Qi = Q^-1, Vv = A Qi, Uu = Vv A' ----
    inv8_lds(Qmat, Qi, W, g, i);
    {
        float a = 0.0f;
#pragma unroll
        for (int k = 0; k < 8; ++k) a += Amat[g][k] * Qi[k][i];
        Vv[g][i] = a;
    }
    __syncthreads();
    {
        float a = 0.0f;
#pragma unroll
        for (int k = 0; k < 8; ++k) a += Vv[g][k] * Amat[i][k];
        Uu[g][i] = a;
    }
    __syncthreads();

    // ---- per-lane register caches ----
    float Qrow[8], Arow[8], AcolT[8], Qirow[8];
    float vvrow[8], vvcol[8], vTrow[8], vTcol[8];
    float Brow[4], brow3[4], Rrow[4], BcolU[8];
#pragma unroll
    for (int k = 0; k < 8; ++k) {
        Qrow[k] = Qmat[i][k]; Arow[k] = Amat[i][k]; AcolT[k] = Amat[k][i];
        Qirow[k] = Qi[i][k];
        vvrow[k] = Vv[g][k]; vvcol[k] = Vv[i][k];
        vTrow[k] = Vv[k][g]; vTcol[k] = Vv[k][i];
        BcolU[k] = Bmat[k][pu];
    }
#pragma unroll
    for (int p = 0; p < 4; ++p) { Brow[p] = Bmat[i][p]; brow3[p] = Bmat[g][p]; Rrow[p] = Rmat[pu][p]; }
    float qi_rc = Qi[g][i], uu_rc = Uu[g][i], vv = Vv[g][i], vv_cr = Vv[i][g];
    float C0 = Cmat[i][0], C1 = Cmat[i][1];

    // ---- b (registers): t=2g (ba), t=2g+1 (bb) ----
    const float* fptr = fg + bi * 32;
    const float* x0p  = x0g + bi * 8;
    float ba = C0 * fptr[4 * g] + C1 * fptr[4 * g + 1];
    float bb = C0 * fptr[4 * g + 2] + C1 * fptr[4 * g + 3];
    if (g == 0) {
#pragma unroll
        for (int j = 0; j < 8; ++j) ba += Arow[j] * x0p[j];
    }

    // ---- state (registers) ----
    float xa = 0.f, xb = 0.f, na = 0.f, nb = 0.f;   // x[2g],x[2g+1],nu[2g],nu[2g+1]
    float ur = 0.f;                                  // u[t_u][pu]
    float s1r = 1.f, s2r = 1.f, l1r = 1.f, l2r = 1.f;
    float da = 0.f, db = 0.f;                        // dnu[2g], dnu[2g+1]

    // ================= IPM iterations =================
#pragma unroll 1
    for (int it = 0; it < ITERS; ++it) {
        float mu = wave_sum64(s1r * l1r + s2r * l2r) * (1.0f / 128.0f);
        float smu = SIGMAF * mu;

        // ---- P1 u-side ----
        float rdu = l1r - l2r;
#pragma unroll
        for (int q = 0; q < 4; ++q) rdu += Rrow[q] * __shfl(ur, g8 + isel + q);
#pragma unroll
        for (int j = 0; j < 8; ++j) {
            float va = __shfl(na, g8 + j), vb = __shfl(nb, g8 + j);
            rdu -= BcolU[j] * (isel ? vb : va);
        }
        float ri1v = ur + s1r - 1.f, ri2v = -ur + s2r - 1.f;
        float rc1v = s1r * l1r - smu, rc2v = s2r * l2r - smu;
        float is1 = __builtin_amdgcn_rcpf(s1r), is2 = __builtin_amdgcn_rcpf(s2r);
        float dd1r = l1r * is1, dd2r = l2r * is2;
        float w1 = (l1r * ri1v - rc1v) * is1, w2 = (l2r * ri2v - rc2v) * is2;
        float rur = -(rdu + w1 - w2);

        // ---- P1 x-side ----
        float rxa = na, rxb = nb;
        float rpa = xa - ba, rpb = xb - bb;
#pragma unroll
        for (int j = 0; j < 8; ++j) {
            float xaj  = __shfl(xa, g8 + j);
            float xbj  = __shfl(xb, g8 + j);
            float nbj  = __shfl(nb, g8 + j);
            float naj1 = __shfl(na, gp1 + j);
            float xbj1 = __shfl(xb, gm1 + j);
            rxa += Qrow[j] * xaj - AcolT[j] * nbj;
            rxb += Qrow[j] * xbj - ((g < 7) ? AcolT[j] * naj1 : 0.f);
            rpb -= Arow[j] * xaj;
            rpa -= (g > 0) ? Arow[j] * xbj1 : 0.f;
        }
#pragma unroll
        for (int p = 0; p < 4; ++p) {
            rpa -= Brow[p] * __shfl(ur, g8 + p);
            rpb -= Brow[p] * __shfl(ur, g8 + 4 + p);
        }
        rxa = -rxa; rxb = -rxb;

        // ---- P2: 16x 4x4 inverses -> Rti (LDS) ----
        __syncthreads();   // protect Rti vs last iter's P7 reads
        {
            int base = (tid >> 1) * 8 + (tid & 1) * 4;
            float Mx[4][4], Iv[4][4];
#pragma unroll
            for (int a = 0; a < 4; ++a)
#pragma unroll
                for (int b = 0; b < 4; ++b) { Mx[a][b] = Rmat[a][b]; Iv[a][b] = (a == b) ? 1.f : 0.f; }
#pragma unroll
            for (int a = 0; a < 4; ++a)
                Mx[a][a] += __shfl(dd1r, base + a) + __shfl(dd2r, base + a);
#pragma unroll
            for (int k = 0; k < 4; ++k) {
                float p = __builtin_amdgcn_rcpf(Mx[k][k]);
#pragma unroll
                for (int b = 0; b < 4; ++b) { Mx[k][b] *= p; Iv[k][b] *= p; }
#pragma unroll
                for (int a = 0; a < 4; ++a) {
                    if (a == k) continue;
                    float m_ = Mx[a][k];
#pragma unroll
                    for (int b = 0; b < 4; ++b) { Mx[a][b] -= m_ * Mx[k][b]; Iv[a][b] -= m_ * Iv[k][b]; }
                }
            }
            if (tid < 16) {
#pragma unroll
                for (int a = 0; a < 4; ++a)
#pragma unroll
                    for (int b = 0; b < 4; ++b) Rti[tid][a * 4 + b] = Iv[a][b];
            }
        }
        // qx (registers, overlap with Rti write latency)
        float qxa = 0.f, qxb = 0.f;
#pragma unroll
        for (int j = 0; j < 8; ++j) {
            qxa += Qirow[j] * __shfl(rxa, g8 + j);
            qxb += Qirow[j] * __shfl(rxb, g8 + j);
        }
        __syncthreads();   // Rti visible

        // ---- P3: qu + Dt blocks ----
        float qur = 0.f;
        {
            int tu16 = (2 * g + (isel ? 1 : 0)) * 16 + pu * 4;
#pragma unroll
            for (int q = 0; q < 4; ++q)
                qur += rti_f[tu16 + q] * __shfl(rur, g8 + isel + q);
        }
        float dt_all[16];
#pragma unroll
        for (int t = 0; t < 16; ++t) {
            float a = qi_rc + (t > 0 ? uu_rc : 0.f);
#pragma unroll
            for (int p = 0; p < 4; ++p) {
                float brp = brow3[p];
#pragma unroll
                for (int q = 0; q < 4; ++q) a += brp * Rti[t][p * 4 + q] * Brow[q];
            }
            dt_all[t] = a;
        }

        // ---- P4: g = Am q + r_p (registers) ----
        float ga_ = qxa + rpa, gb_ = qxb + rpb;
#pragma unroll
        for (int j = 0; j < 8; ++j) {
            ga_ -= (g > 0) ? Arow[j] * __shfl(qxb, gm1 + j) : 0.f;
            gb_ -= Arow[j] * __shfl(qxa, g8 + j);
        }
#pragma unroll
        for (int p = 0; p < 4; ++p) {
            ga_ -= Brow[p] * __shfl(qur, g8 + p);
            gb_ -= Brow[p] * __shfl(qur, g8 + 4 + p);
        }

        // ---- P5: dual-ended block-tridiagonal elimination ----
        float cif_all[8], cib_all[7], yfall[8], yball[7];
        float cif, cib;
        inv8_reg2(dt_all[0], dt_all[15], g, i, cif, cib);
        cif_all[0] = cif; cib_all[0] = cib;
        float ypf = __shfl(ga_, i);          // g[0][c] col-replicated
        float ypb = __shfl(gb_, 56 + i);     // g[15][c]
        yfall[0] = ypf; yball[0] = ypb;
#pragma unroll
        for (int s = 1; s < 7; ++s) {
            float w2f = 0.f, w2b = 0.f;
#pragma unroll
            for (int k = 0; k < 8; ++k) w2f += vvrow[k] * __shfl(cif, k * 8 + i);
#pragma unroll
            for (int k = 0; k < 8; ++k) w2b += vTrow[k] * __shfl(cib, k * 8 + i);
            float ctf = dt_all[s], ctb = dt_all[15 - s];
#pragma unroll
            for (int k = 0; k < 8; ++k) ctf -= __shfl(w2f, g8 + k) * vvcol[k];
#pragma unroll
            for (int k = 0; k < 8; ++k) ctb -= __shfl(w2b, g8 + k) * vTcol[k];
            float prf = w2f * ypf, prb = w2b * ypb;
            prf += __shfl_xor(prf, 1); prf += __shfl_xor(prf, 2); prf += __shfl_xor(prf, 4);
            prb += __shfl_xor(prb, 1); prb += __shfl_xor(prb, 2); prb += __shfl_xor(prb, 4);
            float gsr = (s & 1) ? __shfl(gb_, (s >> 1) * 8 + g) : __shfl(ga_, (s >> 1) * 8 + g);
            float gbr = ((15 - s) & 1) ? __shfl(gb_, ((15 - s) >> 1) * 8 + g)
                                       : __shfl(ga_, ((15 - s) >> 1) * 8 + g);
            float yfrow = gsr + prf;
            float ybrow = gbr + prb;
            ypf = __shfl(yfrow, i * 8);
            ypb = __shfl(ybrow, i * 8);
            yfall[s] = ypf; yball[s] = ypb;
            inv8_reg2(ctf, ctb, g, i, cif, cib);
            cif_all[s] = cif; cib_all[s] = cib;
        }
        // junction: fwd combine t=7; bwd combine t=8; K-solve for dnu[8]
        float x8col;
        {
            float w2f = 0.f, w2b = 0.f;
#pragma unroll
            for (int k = 0; k < 8; ++k) w2f += vvrow[k] * __shfl(cif, k * 8 + i);
#pragma unroll
            for (int k = 0; k < 8; ++k) w2b += vTrow[k] * __shfl(cib, k * 8 + i);
            float ctf = dt_all[7], ctb8 = dt_all[8];
#pragma unroll
            for (int k = 0; k < 8; ++k) ctf -= __shfl(w2f, g8 + k) * vvcol[k];
#pragma unroll
            for (int k = 0; k < 8; ++k) ctb8 -= __shfl(w2b, g8 + k) * vTcol[k];
            float prf = w2f * ypf, prb = w2b * ypb;
            prf += __shfl_xor(prf, 1); prf += __shfl_xor(prf, 2); prf += __shfl_xor(prf, 4);
            prb += __shfl_xor(prb, 1); prb += __shfl_xor(prb, 2); prb += __shfl_xor(prb, 4);
            float yfrow  = __shfl(gb_, 3 * 8 + g) + prf;     // g[7][r]
            float ybrow8 = __shfl(ga_, 4 * 8 + g) + prb;     // g[8][r]
            ypf = __shfl(yfrow, i * 8);
            yfall[7] = ypf;
            cif = inv8_reg(ctf, g, i);
            cif_all[7] = cif;
            float w2K = 0.f;
#pragma unroll
            for (int k = 0; k < 8; ++k) w2K += vvrow[k] * __shfl(cif, k * 8 + i);
            float Kel = ctb8;
#pragma unroll
            for (int k = 0; k < 8; ++k) Kel -= __shfl(w2K, g8 + k) * vvcol[k];
            float prK = w2K * ypf;
            prK += __shfl_xor(prK, 1); prK += __shfl_xor(prK, 2); prK += __shfl_xor(prK, 4);
            float yKrow = ybrow8 + prK;
            float kinv = inv8_reg(Kel, g, i);
            float yKcol = __shfl(yKrow, i * 8);
            float p2 = kinv * yKcol;
            p2 += __shfl_xor(p2, 1); p2 += __shfl_xor(p2, 2); p2 += __shfl_xor(p2, 4);
            // distribute dnu[8] (t=8 even -> da of group 4)
            float v8 = __shfl(p2, i * 8);
            da = (g == 4) ? v8 : da;
            x8col = __shfl(p2, i * 8);
        }
        // ---- P6: dual outward back-substitution ----
        {
            float xlo = x8col, xhi = x8col;
#pragma unroll
            for (int j = 0; j < 8; ++j) {
                // lower: t = 7-j
                {
                    const int t = 7 - j;
                    float dnr = __shfl(xlo, g);
                    float p = vv * dnr;
                    p += __shfl_xor(p, 8); p += __shfl_xor(p, 16); p += __shfl_xor(p, 32);
                    float tvc = yfall[t] + p;
                    float p2l = cif_all[t] * tvc;
                    p2l += __shfl_xor(p2l, 1); p2l += __shfl_xor(p2l, 2); p2l += __shfl_xor(p2l, 4);
                    float v = __shfl(p2l, i * 8);
                    if (t & 1) db = (g == (t >> 1)) ? v : db;
                    else       da = (g == (t >> 1)) ? v : da;
                    xlo = __shfl(p2l, i * 8);
                }
                // upper: t = 9+j
                if (j < 7) {
                    const int t = 9 + j;
                    float xr = __shfl(xhi, g);
                    float pu_ = vv_cr * xr;
                    pu_ += __shfl_xor(pu_, 8); pu_ += __shfl_xor(pu_, 16); pu_ += __shfl_xor(pu_, 32);
                    float tvcu = yball[6 - j] + pu_;
                    float p2u = cib_all[6 - j] * tvcu;
                    p2u += __shfl_xor(p2u, 1); p2u += __shfl_xor(p2u, 2); p2u += __shfl_xor(p2u, 4);
                    float v = __shfl(p2u, i * 8);
                    if (t & 1) db = (g == (t >> 1)) ? v : db;
                    else       da = (g == (t >> 1)) ? v : da;
                    xhi = __shfl(p2u, i * 8);
                }
            }
        }

        // ---- P7: dz = M^-1 (rhs1 - Am' dnu) ----
        float hxa = rxa - da, hxb = rxb - db;
#pragma unroll
        for (int k = 0; k < 8; ++k) {
            hxa += AcolT[k] * __shfl(db, g8 + k);
            hxb += (g < 7) ? AcolT[k] * __shfl(da, gp1 + k) : 0.f;
        }
        float hur = rur;
#pragma unroll
        for (int k = 0; k < 8; ++k) {
            float va = __shfl(da, g8 + k), vb = __shfl(db, g8 + k);
            hur += BcolU[k] * (isel ? vb : va);
        }
        float dxa = 0.f, dxb = 0.f;
#pragma unroll
        for (int j = 0; j < 8; ++j) {
            dxa += Qirow[j] * __shfl(hxa, g8 + j);
            dxb += Qirow[j] * __shfl(hxb, g8 + j);
        }
        float dur = 0.f;
        {
            int tu16 = (2 * g + (isel ? 1 : 0)) * 16 + pu * 4;
#pragma unroll
            for (int q = 0; q < 4; ++q)
                dur += rti_f[tu16 + q] * __shfl(hur, g8 + isel + q);
        }

        // ---- P8: ds, dlam, alpha, update ----
        float dss1 = -ri1v - dur;
        float dss2 = -ri2v + dur;
        float dll1 = (-rc1v - l1r * dss1) * is1;
        float dll2 = (-rc2v - l2r * dss2) * is2;
        float rmin = __builtin_inff();
        if (dss1 < 0.f) rmin = fminf(rmin, -s1r * __builtin_amdgcn_rcpf(dss1));
        if (dss2 < 0.f) rmin = fminf(rmin, -s2r * __builtin_amdgcn_rcpf(dss2));
        if (dll1 < 0.f) rmin = fminf(rmin, -l1r * __builtin_amdgcn_rcpf(dll1));
        if (dll2 < 0.f) rmin = fminf(rmin, -l2r * __builtin_amdgcn_rcpf(dll2));
        rmin = wave_min64(rmin);
        float alpha = fminf(1.f, 0.99f * rmin);

        ur  += alpha * dur;
        s1r += alpha * dss1; s2r += alpha * dss2;
        l1r += alpha * dll1; l2r += alpha * dll2;
        xa  += alpha * dxa;  xb  += alpha * dxb;
        na  += alpha * da;   nb  += alpha * db;
    }

    // ---- outputs: x_sol (128,16,8) then u_sol (128,16,4) ----
    out[bi * 128 + 16 * g + i]     = xa;
    out[bi * 128 + 16 * g + 8 + i] = xb;
    out[16384 + bi * 64 + tid]     = ur;
}

extern "C" void kernel_launch(void* const* d_in, const int* in_sizes, int n_in,
                              void* d_out, int out_size, void* d_ws, size_t ws_size,
                              hipStream_t stream) {
    const float* x0 = (const float*)d_in[0];
    const float* fc = (const float*)d_in[1];
    const float* A  = (const float*)d_in[2];
    const float* B  = (const float*)d_in[3];
    const float* C  = (const float*)d_in[4];
    const float* Q  = (const float*)d_in[5];
    const float* R  = (const float*)d_in[6];
    float* out = (float*)d_out;
    const int batch = in_sizes[0] / 8;  // 128
    mpc_ipm_kernel<<<batch, 64, 0, stream>>>(x0, fc, A, B, C, Q, R, out);
}

// Round 6
// 176.201 us; speedup vs baseline: 2.5061x; 1.0157x over previous
//
#include <hip/hip_runtime.h>
#include <math.h>

#define ITERS 12
#define SIGMAF 0.1f

__device__ inline float wave_min64(float v) {
#pragma unroll
    for (int off = 32; off >= 1; off >>= 1) v = fminf(v, __shfl_xor(v, off));
    return v;
}
__device__ inline float wave_sum64(float v) {
#pragma unroll
    for (int off = 32; off >= 1; off >>= 1) v += __shfl_xor(v, off);
    return v;
}

// Cooperative 8x8 inverse via LDS (setup only).
__device__ void inv8_lds(const float (*src)[8], float (*dst)[8], float (*W)[16],
                         int r, int c) {
    W[r][c]     = src[r][c];
    W[r][c + 8] = (r == c) ? 1.0f : 0.0f;
    __syncthreads();
#pragma unroll
    for (int k = 0; k < 8; ++k) {
        float pinv = 1.0f / W[k][k];
        float m    = W[r][k];
        __syncthreads();
        if (r == k) { W[k][c] *= pinv; W[k][c + 8] *= pinv; }
        __syncthreads();
        float a0 = W[k][c], a1 = W[k][c + 8];
        if (r != k) { W[r][c] -= m * a0; W[r][c + 8] -= m * a1; }
        __syncthreads();
    }
    dst[r][c] = W[r][c + 8];
    __syncthreads();
}

extern "C" __global__ void __launch_bounds__(64, 1)
mpc_ipm_kernel(const float* __restrict__ x0g, const float* __restrict__ fg,
               const float* __restrict__ Ag, const float* __restrict__ Bg,
               const float* __restrict__ Cg, const float* __restrict__ Qg,
               const float* __restrict__ Rg, float* __restrict__ out)
{
    const int bi  = blockIdx.x;
    const int tid = threadIdx.x;
    const int g = tid >> 3, i = tid & 7;     // lane (g,i) = (row, col)
    const int isel = i & 4;                  // u-half selector (0 or 4)
    const int pu = i & 3;
    const int g8 = g * 8;
    const int gp1 = ((g + 1) & 7) * 8, gm1 = ((g - 1) & 7) * 8;

    __shared__ float Amat[8][8], Bmat[8][4], Cmat[8][2], Qmat[8][8], Rmat[4][4];
    __shared__ float Qi[8][8], Vv[8][8], Uu[8][8];
    __shared__ float W[8][16];
    __shared__ float Rti[16][16];
    const float4* rti4 = reinterpret_cast<const float4*>(&Rti[0][0]);

    // ---- load constant matrices ----
    Amat[g][i] = Ag[tid];
    Qmat[g][i] = Qg[tid];
    if (tid < 32) Bmat[tid >> 2][tid & 3] = Bg[tid];
    if (tid < 16) { Cmat[tid >> 1][tid & 1] = Cg[tid]; Rmat[tid >> 2][tid & 3] = Rg[tid]; }
    __syncthreads();

    // ---- Qi = Q^-1, Vv = A Qi, Uu = Vv A' ----
    inv8_lds(Qmat, Qi, W, g, i);
    {
        float a = 0.0f;
#pragma unroll
        for (int k = 0; k < 8; ++k) a += Amat[g][k] * Qi[k][i];
        Vv[g][i] = a;
    }
    __syncthreads();
    {
        float a = 0.0f;
#pragma unroll
        for (int k = 0; k < 8; ++k) a += Vv[g][k] * Amat[i][k];
        Uu[g][i] = a;
    }
    __syncthreads();

    // ---- per-lane register caches ----
    float Qrow[8], Arow[8], AcolT[8], Qirow[8];
    float vvrow[8], vTrow[8];
    float Brow[4], brow3[4], Rrow[4], BcolU[8];
#pragma unroll
    for (int k = 0; k < 8; ++k) {
        Qrow[k] = Qmat[i][k]; Arow[k] = Amat[i][k]; AcolT[k] = Amat[k][i];
        Qirow[k] = Qi[i][k];
        vvrow[k] = Vv[g][k];        // V[r][k]
        vTrow[k] = Vv[k][g];        // V[k][r]
        BcolU[k] = Bmat[k][pu];
    }
#pragma unroll
    for (int p = 0; p < 4; ++p) { Brow[p] = Bmat[i][p]; brow3[p] = Bmat[g][p]; Rrow[p] = Rmat[pu][p]; }
    float qi_rc = Qi[g][i], uu_rc = Uu[g][i];
    float vv = Vv[g][i];            // V[r][c]
    float vv_cr = Vv[i][g];         // V[c][r] = (V^T)[r][c]
    float C0 = Cmat[i][0], C1 = Cmat[i][1];

    // ---- b (registers): t=2g (ba), t=2g+1 (bb) ----
    const float* fptr = fg + bi * 32;
    const float* x0p  = x0g + bi * 8;
    float ba = C0 * fptr[4 * g] + C1 * fptr[4 * g + 1];
    float bb = C0 * fptr[4 * g + 2] + C1 * fptr[4 * g + 3];
    if (g == 0) {
#pragma unroll
        for (int j = 0; j < 8; ++j) ba += Arow[j] * x0p[j];
    }

    // ---- state (registers) ----
    float xa = 0.f, xb = 0.f, na = 0.f, nb = 0.f;
    float ur = 0.f;
    float s1r = 1.f, s2r = 1.f, l1r = 1.f, l2r = 1.f;
    float da = 0.f, db = 0.f;

    // ================= IPM iterations =================
#pragma unroll 1
    for (int it = 0; it < ITERS; ++it) {
        float mu = wave_sum64(s1r * l1r + s2r * l2r) * (1.0f / 128.0f);
        float smu = SIGMAF * mu;

        // ---- P1 u-side ----
        float rdu = l1r - l2r;
#pragma unroll
        for (int q = 0; q < 4; ++q) rdu += Rrow[q] * __shfl(ur, g8 + isel + q);
#pragma unroll
        for (int j = 0; j < 8; ++j) {
            float va = __shfl(na, g8 + j), vb = __shfl(nb, g8 + j);
            rdu -= BcolU[j] * (isel ? vb : va);
        }
        float ri1v = ur + s1r - 1.f, ri2v = -ur + s2r - 1.f;
        float rc1v = s1r * l1r - smu, rc2v = s2r * l2r - smu;
        float is1 = __builtin_amdgcn_rcpf(s1r), is2 = __builtin_amdgcn_rcpf(s2r);
        float dd1r = l1r * is1, dd2r = l2r * is2;
        float w1 = (l1r * ri1v - rc1v) * is1, w2 = (l2r * ri2v - rc2v) * is2;
        float rur = -(rdu + w1 - w2);

        // ---- P1 x-side ----
        float rxa = na, rxb = nb;
        float rpa = xa - ba, rpb = xb - bb;
#pragma unroll
        for (int j = 0; j < 8; ++j) {
            float xaj  = __shfl(xa, g8 + j);
            float xbj  = __shfl(xb, g8 + j);
            float nbj  = __shfl(nb, g8 + j);
            float naj1 = __shfl(na, gp1 + j);
            float xbj1 = __shfl(xb, gm1 + j);
            rxa += Qrow[j] * xaj - AcolT[j] * nbj;
            rxb += Qrow[j] * xbj - ((g < 7) ? AcolT[j] * naj1 : 0.f);
            rpb -= Arow[j] * xaj;
            rpa -= (g > 0) ? Arow[j] * xbj1 : 0.f;
        }
#pragma unroll
        for (int p = 0; p < 4; ++p) {
            rpa -= Brow[p] * __shfl(ur, g8 + p);
            rpb -= Brow[p] * __shfl(ur, g8 + 4 + p);
        }
        rxa = -rxa; rxb = -rxb;

        // ---- P2: 16x 4x4 inverses -> Rti (LDS) ----
        __syncthreads();   // protect Rti vs last iter's P7 reads
        {
            int base = (tid >> 1) * 8 + (tid & 1) * 4;
            float Mx[4][4], Iv[4][4];
#pragma unroll
            for (int a = 0; a < 4; ++a)
#pragma unroll
                for (int b = 0; b < 4; ++b) { Mx[a][b] = Rmat[a][b]; Iv[a][b] = (a == b) ? 1.f : 0.f; }
#pragma unroll
            for (int a = 0; a < 4; ++a)
                Mx[a][a] += __shfl(dd1r, base + a) + __shfl(dd2r, base + a);
#pragma unroll
            for (int k = 0; k < 4; ++k) {
                float p = __builtin_amdgcn_rcpf(Mx[k][k]);
#pragma unroll
                for (int b = 0; b < 4; ++b) { Mx[k][b] *= p; Iv[k][b] *= p; }
#pragma unroll
                for (int a = 0; a < 4; ++a) {
                    if (a == k) continue;
                    float m_ = Mx[a][k];
#pragma unroll
                    for (int b = 0; b < 4; ++b) { Mx[a][b] -= m_ * Mx[k][b]; Iv[a][b] -= m_ * Iv[k][b]; }
                }
            }
            if (tid < 16) {
#pragma unroll
                for (int a = 0; a < 4; ++a)
#pragma unroll
                    for (int b = 0; b < 4; ++b) Rti[tid][a * 4 + b] = Iv[a][b];
            }
        }
        // qx (registers; overlaps Rti write latency)
        float qxa = 0.f, qxb = 0.f;
#pragma unroll
        for (int j = 0; j < 8; ++j) {
            qxa += Qirow[j] * __shfl(rxa, g8 + j);
            qxb += Qirow[j] * __shfl(rxb, g8 + j);
        }
        __syncthreads();   // Rti visible

        // ---- P3: qu + Dt blocks (float4 LDS broadcast reads) ----
        float qur;
        {
            float4 rr = rti4[(2 * g + (isel ? 1 : 0)) * 4 + pu];
            qur = rr.x * __shfl(rur, g8 + isel)
                + rr.y * __shfl(rur, g8 + isel + 1)
                + rr.z * __shfl(rur, g8 + isel + 2)
                + rr.w * __shfl(rur, g8 + isel + 3);
        }
        float dt_all[16];
#pragma unroll
        for (int t = 0; t < 16; ++t) {
            float a = qi_rc + (t > 0 ? uu_rc : 0.f);
#pragma unroll
            for (int p = 0; p < 4; ++p) {
                float4 rp4 = rti4[t * 4 + p];
                a += brow3[p] * (rp4.x * Brow[0] + rp4.y * Brow[1]
                               + rp4.z * Brow[2] + rp4.w * Brow[3]);
            }
            dt_all[t] = a;
        }

        // ---- P4: g = Am q + r_p (registers) ----
        float ga_ = qxa + rpa, gb_ = qxb + rpb;
#pragma unroll
        for (int j = 0; j < 8; ++j) {
            ga_ -= (g > 0) ? Arow[j] * __shfl(qxb, gm1 + j) : 0.f;
            gb_ -= Arow[j] * __shfl(qxa, g8 + j);
        }
#pragma unroll
        for (int p = 0; p < 4; ++p) {
            ga_ -= Brow[p] * __shfl(qur, g8 + p);
            gb_ -= Brow[p] * __shfl(qur, g8 + 4 + p);
        }

        // ---- P5: dual-ended AUGMENTED-GJ sweep.
        //      fwd stage t: solve Cf_t·[Xf|zf] = [V^T|y_t]  (8 levels)
        //      next: Cf_{t+1} = D_{t+1} - V·Xf ; y_{t+1} = g_{t+1} + V·zf (1 level)
        //      bwd mirror with V <-> V^T. Zero barriers. ----
        float grall[16];
#pragma unroll
        for (int t = 0; t < 16; ++t)
            grall[t] = (t & 1) ? __shfl(gb_, (t >> 1) * 8 + g)
                               : __shfl(ga_, (t >> 1) * 8 + g);   // g_t[r], row-rep

        float xf_all[8], zf_all[8], xb_all[7], zb_all[7];
        float wf = dt_all[0], wb = dt_all[15];
        float yf = grall[0], yb = grall[15];
#pragma unroll
        for (int s = 0; s < 7; ++s) {
            float xfv = vv_cr, zfv = yf;
            float xbv = vv,   zbv = yb;
#pragma unroll
            for (int k = 0; k < 8; ++k) {
                float fkk = __shfl(wf, k * 9),     bkk = __shfl(wb, k * 9);
                float fm  = __shfl(wf, g8 + k),    bm  = __shfl(wb, g8 + k);
                float fkc = __shfl(wf, k * 8 + i), bkc = __shfl(wb, k * 8 + i);
                float fxk = __shfl(xfv, k * 8 + i), bxk = __shfl(xbv, k * 8 + i);
                float fzk = __shfl(zfv, k * 8),     bzk = __shfl(zbv, k * 8);
                float fp = __builtin_amdgcn_rcpf(fkk), bp = __builtin_amdgcn_rcpf(bkk);
                float fws = fkc * fp, bws = bkc * bp;
                float fxs = fxk * fp, bxs = bxk * bp;
                float fzs = fzk * fp, bzs = bzk * bp;
                bool diag = (g == k);
                wf  = diag ? fws : wf  - fm * fws;
                xfv = diag ? fxs : xfv - fm * fxs;
                zfv = diag ? fzs : zfv - fm * fzs;
                wb  = diag ? bws : wb  - bm * bws;
                xbv = diag ? bxs : xbv - bm * bxs;
                zbv = diag ? bzs : zbv - bm * bzs;
            }
            xf_all[s] = xfv; zf_all[s] = zfv;
            xb_all[s] = xbv; zb_all[s] = zbv;
            float cf = dt_all[s + 1],  cb = dt_all[14 - s];
            float yfn = grall[s + 1],  ybn = grall[14 - s];
#pragma unroll
            for (int k = 0; k < 8; ++k) {
                cf  -= vvrow[k] * __shfl(xfv, k * 8 + i);
                yfn += vvrow[k] * __shfl(zfv, k * 8);
                cb  -= vTrow[k] * __shfl(xbv, k * 8 + i);
                ybn += vTrow[k] * __shfl(zbv, k * 8);
            }
            wf = cf; yf = yfn; wb = cb; yb = ybn;
        }
        // fwd stage t=7 (single, augmented)
        {
            float xfv = vv_cr, zfv = yf;
#pragma unroll
            for (int k = 0; k < 8; ++k) {
                float fkk = __shfl(wf, k * 9);
                float fm  = __shfl(wf, g8 + k);
                float fkc = __shfl(wf, k * 8 + i);
                float fxk = __shfl(xfv, k * 8 + i);
                float fzk = __shfl(zfv, k * 8);
                float fp = __builtin_amdgcn_rcpf(fkk);
                float fws = fkc * fp, fxs = fxk * fp, fzs = fzk * fp;
                bool diag = (g == k);
                wf  = diag ? fws : wf  - fm * fws;
                xfv = diag ? fxs : xfv - fm * fxs;
                zfv = diag ? fzs : zfv - fm * fzs;
            }
            xf_all[7] = xfv; zf_all[7] = zfv;
        }
        // junction t=8: (after s=6 combine, wb = D8 - V^T·Xb9, yb = g8 + V^T·zb9)
        float x8c;
        {
            float w8 = wb, y8 = yb;
#pragma unroll
            for (int k = 0; k < 8; ++k) {
                w8 -= vvrow[k] * __shfl(xf_all[7], k * 8 + i);
                y8 += vvrow[k] * __shfl(zf_all[7], k * 8);
            }
            float x8r = y8;   // z-only GJ solve: x8 = w8^-1 y8
#pragma unroll
            for (int k = 0; k < 8; ++k) {
                float kk = __shfl(w8, k * 9);
                float m_ = __shfl(w8, g8 + k);
                float kc = __shfl(w8, k * 8 + i);
                float zk = __shfl(x8r, k * 8);
                float p = __builtin_amdgcn_rcpf(kk);
                float ws = kc * p, zs = zk * p;
                bool diag = (g == k);
                w8  = diag ? ws : w8  - m_ * ws;
                x8r = diag ? zs : x8r - m_ * zs;
            }
            x8c = __shfl(x8r, i * 8);          // col-rep
            da = (g == 4) ? x8c : da;          // dnu[8]
        }
        // ---- P6: dual outward back-substitution: x_t = z_t + X_t·x_adj ----
        {
            float xcl = x8c, xcu = x8c;
#pragma unroll
            for (int j = 0; j < 8; ++j) {
                {
                    const int t = 7 - j;
                    float p = xf_all[t] * xcl;
                    p += __shfl_xor(p, 1); p += __shfl_xor(p, 2); p += __shfl_xor(p, 4);
                    float xr = zf_all[t] + p;          // row-rep
                    float xc = __shfl(xr, i * 8);      // col-rep
                    if (t & 1) db = (g == (t >> 1)) ? xc : db;
                    else       da = (g == (t >> 1)) ? xc : da;
                    xcl = xc;
                }
                if (j < 7) {
                    const int t = 9 + j;               // xb index s = 6-j
                    float p = xb_all[6 - j] * xcu;
                    p += __shfl_xor(p, 1); p += __shfl_xor(p, 2); p += __shfl_xor(p, 4);
                    float xr = zb_all[6 - j] + p;
                    float xc = __shfl(xr, i * 8);
                    if (t & 1) db = (g == (t >> 1)) ? xc : db;
                    else       da = (g == (t >> 1)) ? xc : da;
                    xcu = xc;
                }
            }
        }

        // ---- P7: dz = M^-1 (rhs1 - Am' dnu) ----
        float hxa = rxa - da, hxb = rxb - db;
#pragma unroll
        for (int k = 0; k < 8; ++k) {
            hxa += AcolT[k] * __shfl(db, g8 + k);
            hxb += (g < 7) ? AcolT[k] * __shfl(da, gp1 + k) : 0.f;
        }
        float hur = rur;
#pragma unroll
        for (int k = 0; k < 8; ++k) {
            float va = __shfl(da, g8 + k), vb = __shfl(db, g8 + k);
            hur += BcolU[k] * (isel ? vb : va);
        }
        float dxa = 0.f, dxb = 0.f;
#pragma unroll
        for (int j = 0; j < 8; ++j) {
            dxa += Qirow[j] * __shfl(hxa, g8 + j);
            dxb += Qirow[j] * __shfl(hxb, g8 + j);
        }
        float dur;
        {
            float4 rr = rti4[(2 * g + (isel ? 1 : 0)) * 4 + pu];
            dur = rr.x * __shfl(hur, g8 + isel)
                + rr.y * __shfl(hur, g8 + isel + 1)
                + rr.z * __shfl(hur, g8 + isel + 2)
                + rr.w * __shfl(hur, g8 + isel + 3);
        }

        // ---- P8: ds, dlam, alpha, update ----
        float dss1 = -ri1v - dur;
        float dss2 = -ri2v + dur;
        float dll1 = (-rc1v - l1r * dss1) * is1;
        float dll2 = (-rc2v - l2r * dss2) * is2;
        float rmin = __builtin_inff();
        if (dss1 < 0.f) rmin = fminf(rmin, -s1r * __builtin_amdgcn_rcpf(dss1));
        if (dss2 < 0.f) rmin = fminf(rmin, -s2r * __builtin_amdgcn_rcpf(dss2));
        if (dll1 < 0.f) rmin = fminf(rmin, -l1r * __builtin_amdgcn_rcpf(dll1));
        if (dll2 < 0.f) rmin = fminf(rmin, -l2r * __builtin_amdgcn_rcpf(dll2));
        rmin = wave_min64(rmin);
        float alpha = fminf(1.f, 0.99f * rmin);

        ur  += alpha * dur;
        s1r += alpha * dss1; s2r += alpha * dss2;
        l1r += alpha * dll1; l2r += alpha * dll2;
        xa  += alpha * dxa;  xb  += alpha * dxb;
        na  += alpha * da;   nb  += alpha * db;
    }

    // ---- outputs: x_sol (128,16,8) then u_sol (128,16,4) ----
    out[bi * 128 + 16 * g + i]     = xa;
    out[bi * 128 + 16 * g + 8 + i] = xb;
    out[16384 + bi * 64 + tid]     = ur;
}

extern "C" void kernel_launch(void* const* d_in, const int* in_sizes, int n_in,
                              void* d_out, int out_size, void* d_ws, size_t ws_size,
                              hipStream_t stream) {
    const float* x0 = (const float*)d_in[0];
    const float* fc = (const float*)d_in[1];
    const float* A  = (const float*)d_in[2];
    const float* B  = (const float*)d_in[3];
    const float* C  = (const float*)d_in[4];
    const float* Q  = (const float*)d_in[5];
    const float* R  = (const float*)d_in[6];
    float* out = (float*)d_out;
    const int batch = in_sizes[0] / 8;  // 128
    mpc_ipm_kernel<<<batch, 64, 0, stream>>>(x0, fc, A, B, C, Q, R, out);
}

// Round 7
// 160.253 us; speedup vs baseline: 2.7555x; 1.0995x over previous
//
#include <hip/hip_runtime.h>
#include <math.h>

#define ITERS 12
#define SIGMAF 0.1f

__device__ inline float rdl(float v, int l) {
    return __int_as_float(__builtin_amdgcn_readlane(__float_as_int(v), l));
}
template <int CTRL>
__device__ inline float dppf(float v) {
    return __int_as_float(__builtin_amdgcn_update_dpp(0, __float_as_int(v), CTRL, 0xF, 0xF, true));
}
// sum over each 8-lane row-group (result replicated in the 8 lanes)
__device__ inline float sum8_dpp(float p) {
    p += dppf<0xB1>(p);    // quad_perm [1,0,3,2]  : xor1
    p += dppf<0x4E>(p);    // quad_perm [2,3,0,1]  : xor2
    p += dppf<0x141>(p);   // row_half_mirror      : xor4 (quad-replicated)
    return p;
}
__device__ inline float wsum64_fast(float v) {
    v += dppf<0xB1>(v); v += dppf<0x4E>(v); v += dppf<0x141>(v);
    v += dppf<0x128>(v);   // row_ror:8            : xor8 (8-replicated)
    return (rdl(v, 0) + rdl(v, 16)) + (rdl(v, 32) + rdl(v, 48));
}
__device__ inline float wmin64_fast(float v) {
    v = fminf(v, dppf<0xB1>(v)); v = fminf(v, dppf<0x4E>(v));
    v = fminf(v, dppf<0x141>(v)); v = fminf(v, dppf<0x128>(v));
    return fminf(fminf(rdl(v, 0), rdl(v, 16)), fminf(rdl(v, 32), rdl(v, 48)));
}

// Cooperative 8x8 inverse via LDS (setup only).
__device__ void inv8_lds(const float (*src)[8], float (*dst)[8], float (*W)[16],
                         int r, int c) {
    W[r][c]     = src[r][c];
    W[r][c + 8] = (r == c) ? 1.0f : 0.0f;
    __syncthreads();
#pragma unroll
    for (int k = 0; k < 8; ++k) {
        float pinv = 1.0f / W[k][k];
        float m    = W[r][k];
        __syncthreads();
        if (r == k) { W[k][c] *= pinv; W[k][c + 8] *= pinv; }
        __syncthreads();
        float a0 = W[k][c], a1 = W[k][c + 8];
        if (r != k) { W[r][c] -= m * a0; W[r][c + 8] -= m * a1; }
        __syncthreads();
    }
    dst[r][c] = W[r][c + 8];
    __syncthreads();
}

extern "C" __global__ void __launch_bounds__(64, 1)
mpc_ipm_kernel(const float* __restrict__ x0g, const float* __restrict__ fg,
               const float* __restrict__ Ag, const float* __restrict__ Bg,
               const float* __restrict__ Cg, const float* __restrict__ Qg,
               const float* __restrict__ Rg, float* __restrict__ out)
{
    const int bi  = blockIdx.x;
    const int tid = threadIdx.x;
    const int g = tid >> 3, i = tid & 7;     // lane (g,i) = (row, col)
    const int isel = i & 4;
    const int pu = i & 3;
    const int g8 = g * 8;
    const int gp1 = ((g + 1) & 7) * 8, gm1 = ((g - 1) & 7) * 8;

    __shared__ float Amat[8][8], Bmat[8][4], Cmat[8][2], Qmat[8][8], Rmat[4][4];
    __shared__ float Qi[8][8], Vv[8][8], Uu[8][8];
    __shared__ float W[8][16];
    __shared__ float Rti[16][16];
    const float4* rti4 = reinterpret_cast<const float4*>(&Rti[0][0]);

    Amat[g][i] = Ag[tid];
    Qmat[g][i] = Qg[tid];
    if (tid < 32) Bmat[tid >> 2][tid & 3] = Bg[tid];
    if (tid < 16) { Cmat[tid >> 1][tid & 1] = Cg[tid]; Rmat[tid >> 2][tid & 3] = Rg[tid]; }
    __syncthreads();

    inv8_lds(Qmat, Qi, W, g, i);
    {
        float a = 0.0f;
#pragma unroll
        for (int k = 0; k < 8; ++k) a += Amat[g][k] * Qi[k][i];
        Vv[g][i] = a;
    }
    __syncthreads();
    {
        float a = 0.0f;
#pragma unroll
        for (int k = 0; k < 8; ++k) a += Vv[g][k] * Amat[i][k];
        Uu[g][i] = a;
    }
    __syncthreads();

    float Qrow[8], Arow[8], AcolT[8], Qirow[8];
    float vvrow[8], vTrow[8];
    float Brow[4], brow3[4], Rrow[4], BcolU[8];
#pragma unroll
    for (int k = 0; k < 8; ++k) {
        Qrow[k] = Qmat[i][k]; Arow[k] = Amat[i][k]; AcolT[k] = Amat[k][i];
        Qirow[k] = Qi[i][k];
        vvrow[k] = Vv[g][k];
        vTrow[k] = Vv[k][g];
        BcolU[k] = Bmat[k][pu];
    }
#pragma unroll
    for (int p = 0; p < 4; ++p) { Brow[p] = Bmat[i][p]; brow3[p] = Bmat[g][p]; Rrow[p] = Rmat[pu][p]; }
    float qi_rc = Qi[g][i], uu_rc = Uu[g][i];
    float vv = Vv[g][i];            // V[r][c]
    float vv_cr = Vv[i][g];         // V^T[r][c]
    float C0 = Cmat[i][0], C1 = Cmat[i][1];

    const float* fptr = fg + bi * 32;
    const float* x0p  = x0g + bi * 8;
    float ba = C0 * fptr[4 * g] + C1 * fptr[4 * g + 1];
    float bb = C0 * fptr[4 * g + 2] + C1 * fptr[4 * g + 3];
    if (g == 0) {
#pragma unroll
        for (int j = 0; j < 8; ++j) ba += Arow[j] * x0p[j];
    }

    float xa = 0.f, xb = 0.f, na = 0.f, nb = 0.f;
    float ur = 0.f;
    float s1r = 1.f, s2r = 1.f, l1r = 1.f, l2r = 1.f;
    float da = 0.f, db = 0.f;

#pragma unroll 1
    for (int it = 0; it < ITERS; ++it) {
        float mu = wsum64_fast(s1r * l1r + s2r * l2r) * (1.0f / 128.0f);
        float smu = SIGMAF * mu;

        // ---- P1 u-side ----
        float rdu = l1r - l2r;
#pragma unroll
        for (int q = 0; q < 4; ++q) rdu += Rrow[q] * __shfl(ur, g8 + isel + q);
#pragma unroll
        for (int j = 0; j < 8; ++j) {
            float va = __shfl(na, g8 + j), vb = __shfl(nb, g8 + j);
            rdu -= BcolU[j] * (isel ? vb : va);
        }
        float ri1v = ur + s1r - 1.f, ri2v = -ur + s2r - 1.f;
        float rc1v = s1r * l1r - smu, rc2v = s2r * l2r - smu;
        float is1 = __builtin_amdgcn_rcpf(s1r), is2 = __builtin_amdgcn_rcpf(s2r);
        float dd1r = l1r * is1, dd2r = l2r * is2;
        float w1 = (l1r * ri1v - rc1v) * is1, w2 = (l2r * ri2v - rc2v) * is2;
        float rur = -(rdu + w1 - w2);

        // ---- P1 x-side ----
        float rxa = na, rxb = nb;
        float rpa = xa - ba, rpb = xb - bb;
#pragma unroll
        for (int j = 0; j < 8; ++j) {
            float xaj  = __shfl(xa, g8 + j);
            float xbj  = __shfl(xb, g8 + j);
            float nbj  = __shfl(nb, g8 + j);
            float naj1 = __shfl(na, gp1 + j);
            float xbj1 = __shfl(xb, gm1 + j);
            rxa += Qrow[j] * xaj - AcolT[j] * nbj;
            rxb += Qrow[j] * xbj - ((g < 7) ? AcolT[j] * naj1 : 0.f);
            rpb -= Arow[j] * xaj;
            rpa -= (g > 0) ? Arow[j] * xbj1 : 0.f;
        }
#pragma unroll
        for (int p = 0; p < 4; ++p) {
            rpa -= Brow[p] * __shfl(ur, g8 + p);
            rpb -= Brow[p] * __shfl(ur, g8 + 4 + p);
        }
        rxa = -rxa; rxb = -rxb;

        // ---- P2: 16x 4x4 inverses -> Rti (LDS) ----
        __syncthreads();
        {
            int base = (tid >> 1) * 8 + (tid & 1) * 4;
            float Mx[4][4], Iv[4][4];
#pragma unroll
            for (int a = 0; a < 4; ++a)
#pragma unroll
                for (int b = 0; b < 4; ++b) { Mx[a][b] = Rmat[a][b]; Iv[a][b] = (a == b) ? 1.f : 0.f; }
#pragma unroll
            for (int a = 0; a < 4; ++a)
                Mx[a][a] += __shfl(dd1r, base + a) + __shfl(dd2r, base + a);
#pragma unroll
            for (int k = 0; k < 4; ++k) {
                float p = __builtin_amdgcn_rcpf(Mx[k][k]);
#pragma unroll
                for (int b = 0; b < 4; ++b) { Mx[k][b] *= p; Iv[k][b] *= p; }
#pragma unroll
                for (int a = 0; a < 4; ++a) {
                    if (a == k) continue;
                    float m_ = Mx[a][k];
#pragma unroll
                    for (int b = 0; b < 4; ++b) { Mx[a][b] -= m_ * Mx[k][b]; Iv[a][b] -= m_ * Iv[k][b]; }
                }
            }
            if (tid < 16) {
#pragma unroll
                for (int a = 0; a < 4; ++a)
#pragma unroll
                    for (int b = 0; b < 4; ++b) Rti[tid][a * 4 + b] = Iv[a][b];
            }
        }
        float qxa = 0.f, qxb = 0.f;
#pragma unroll
        for (int j = 0; j < 8; ++j) {
            qxa += Qirow[j] * __shfl(rxa, g8 + j);
            qxb += Qirow[j] * __shfl(rxb, g8 + j);
        }
        __syncthreads();

        // ---- P3: qu + Dt blocks ----
        float qur;
        {
            float4 rr = rti4[(2 * g + (isel ? 1 : 0)) * 4 + pu];
            qur = rr.x * __shfl(rur, g8 + isel)
                + rr.y * __shfl(rur, g8 + isel + 1)
                + rr.z * __shfl(rur, g8 + isel + 2)
                + rr.w * __shfl(rur, g8 + isel + 3);
        }
        float dt_all[16];
#pragma unroll
        for (int t = 0; t < 16; ++t) {
            float a = qi_rc + (t > 0 ? uu_rc : 0.f);
#pragma unroll
            for (int p = 0; p < 4; ++p) {
                float4 rp4 = rti4[t * 4 + p];
                a += brow3[p] * (rp4.x * Brow[0] + rp4.y * Brow[1]
                               + rp4.z * Brow[2] + rp4.w * Brow[3]);
            }
            dt_all[t] = a;
        }

        // ---- P4: g = Am q + r_p ----
        float ga_ = qxa + rpa, gb_ = qxb + rpb;
#pragma unroll
        for (int j = 0; j < 8; ++j) {
            ga_ -= (g > 0) ? Arow[j] * __shfl(qxb, gm1 + j) : 0.f;
            gb_ -= Arow[j] * __shfl(qxa, g8 + j);
        }
#pragma unroll
        for (int p = 0; p < 4; ++p) {
            ga_ -= Brow[p] * __shfl(qur, g8 + p);
            gb_ -= Brow[p] * __shfl(qur, g8 + 4 + p);
        }

        // ---- P5: dual-ended sweep, 2x2-block GJ (4 crossbar rounds/solve).
        //      fwd: Cf_t·[X|z]=[V^T|y] ; bwd mirror with V<->V^T. ----
        float grall[16];
#pragma unroll
        for (int t = 0; t < 16; ++t)
            grall[t] = (t & 1) ? __shfl(gb_, (t >> 1) * 8 + g)
                               : __shfl(ga_, (t >> 1) * 8 + g);   // row-rep

        float xf_all[8], zf_all[8], xb_all[7], zb_all[7];
        float wf = dt_all[0], wb = dt_all[15];
        float zf = grall[0], zb = grall[15];
#pragma unroll
        for (int s = 0; s < 7; ++s) {
            float xf = vv_cr, xbv = vv;
#pragma unroll
            for (int l = 0; l < 4; ++l) {
                const int ra = 2 * l, rb = 2 * l + 1;
                float fp00 = rdl(wf, ra * 9), fp01 = rdl(wf, ra * 8 + rb);
                float fp10 = rdl(wf, rb * 8 + ra), fp11 = rdl(wf, rb * 9);
                float bq00 = rdl(wb, ra * 9), bq01 = rdl(wb, ra * 8 + rb);
                float bq10 = rdl(wb, rb * 8 + ra), bq11 = rdl(wb, rb * 9);
                float fza = rdl(zf, ra * 8), fzb = rdl(zf, rb * 8);
                float bza = rdl(zb, ra * 8), bzb = rdl(zb, rb * 8);
                float frka = __shfl(wf, ra * 8 + i), frkb = __shfl(wf, rb * 8 + i);
                float brka = __shfl(wb, ra * 8 + i), brkb = __shfl(wb, rb * 8 + i);
                float fxka = __shfl(xf, ra * 8 + i), fxkb = __shfl(xf, rb * 8 + i);
                float bxka = __shfl(xbv, ra * 8 + i), bxkb = __shfl(xbv, rb * 8 + i);
                float fma_ = __shfl(wf, g8 + ra), fmb_ = __shfl(wf, g8 + rb);
                float bma_ = __shfl(wb, g8 + ra), bmb_ = __shfl(wb, g8 + rb);
                float fdi = __builtin_amdgcn_rcpf(fp00 * fp11 - fp01 * fp10);
                float bdi = __builtin_amdgcn_rcpf(bq00 * bq11 - bq01 * bq10);
                float fi00 = fp11 * fdi, fi01 = -fp01 * fdi, fi10 = -fp10 * fdi, fi11 = fp00 * fdi;
                float bi00 = bq11 * bdi, bi01 = -bq01 * bdi, bi10 = -bq10 * bdi, bi11 = bq00 * bdi;
                float fsra = fi00 * frka + fi01 * frkb, fsrb = fi10 * frka + fi11 * frkb;
                float fsxa = fi00 * fxka + fi01 * fxkb, fsxb = fi10 * fxka + fi11 * fxkb;
                float fsza = fi00 * fza  + fi01 * fzb , fszb = fi10 * fza  + fi11 * fzb ;
                float bsra = bi00 * brka + bi01 * brkb, bsrb = bi10 * brka + bi11 * brkb;
                float bsxa = bi00 * bxka + bi01 * bxkb, bsxb = bi10 * bxka + bi11 * bxkb;
                float bsza = bi00 * bza  + bi01 * bzb , bszb = bi10 * bza  + bi11 * bzb ;
                bool pa = (g == ra), pb = (g == rb);
                float wfn = wf - fma_ * fsra - fmb_ * fsrb;
                float xfn = xf - fma_ * fsxa - fmb_ * fsxb;
                float zfn = zf - fma_ * fsza - fmb_ * fszb;
                wf = pa ? fsra : pb ? fsrb : wfn;
                xf = pa ? fsxa : pb ? fsxb : xfn;
                zf = pa ? fsza : pb ? fszb : zfn;
                float wbn = wb - bma_ * bsra - bmb_ * bsrb;
                float xbn = xbv - bma_ * bsxa - bmb_ * bsxb;
                float zbn = zb - bma_ * bsza - bmb_ * bszb;
                wb  = pa ? bsra : pb ? bsrb : wbn;
                xbv = pa ? bsxa : pb ? bsxb : xbn;
                zb  = pa ? bsza : pb ? bszb : zbn;
            }
            xf_all[s] = xf; zf_all[s] = zf; xb_all[s] = xbv; zb_all[s] = zb;
            float cf = dt_all[s + 1], cb = dt_all[14 - s];
            float yfn = grall[s + 1], ybn = grall[14 - s];
#pragma unroll
            for (int k = 0; k < 8; ++k) {
                cf  -= vvrow[k] * __shfl(xf, k * 8 + i);
                yfn += vvrow[k] * rdl(zf, k * 8);
                cb  -= vTrow[k] * __shfl(xbv, k * 8 + i);
                ybn += vTrow[k] * rdl(zb, k * 8);
            }
            wf = cf; zf = yfn; wb = cb; zb = ybn;
        }
        // fwd stage t=7 (single)
        {
            float xf = vv_cr;
#pragma unroll
            for (int l = 0; l < 4; ++l) {
                const int ra = 2 * l, rb = 2 * l + 1;
                float fp00 = rdl(wf, ra * 9), fp01 = rdl(wf, ra * 8 + rb);
                float fp10 = rdl(wf, rb * 8 + ra), fp11 = rdl(wf, rb * 9);
                float fza = rdl(zf, ra * 8), fzb = rdl(zf, rb * 8);
                float frka = __shfl(wf, ra * 8 + i), frkb = __shfl(wf, rb * 8 + i);
                float fxka = __shfl(xf, ra * 8 + i), fxkb = __shfl(xf, rb * 8 + i);
                float fma_ = __shfl(wf, g8 + ra), fmb_ = __shfl(wf, g8 + rb);
                float fdi = __builtin_amdgcn_rcpf(fp00 * fp11 - fp01 * fp10);
                float fi00 = fp11 * fdi, fi01 = -fp01 * fdi, fi10 = -fp10 * fdi, fi11 = fp00 * fdi;
                float fsra = fi00 * frka + fi01 * frkb, fsrb = fi10 * frka + fi11 * frkb;
                float fsxa = fi00 * fxka + fi01 * fxkb, fsxb = fi10 * fxka + fi11 * fxkb;
                float fsza = fi00 * fza  + fi01 * fzb , fszb = fi10 * fza  + fi11 * fzb ;
                bool pa = (g == ra), pb = (g == rb);
                float wfn = wf - fma_ * fsra - fmb_ * fsrb;
                float xfn = xf - fma_ * fsxa - fmb_ * fsxb;
                float zfn = zf - fma_ * fsza - fmb_ * fszb;
                wf = pa ? fsra : pb ? fsrb : wfn;
                xf = pa ? fsxa : pb ? fsxb : xfn;
                zf = pa ? fsza : pb ? fszb : zfn;
            }
            xf_all[7] = xf; zf_all[7] = zf;
        }
        // junction t=8: w8 = C~8 - V·Xf7 ; y8 = y~8 + V·zf7 ; solve w8 x8 = y8
        float x8c;
        {
            float w8 = wb, y8 = zb;
#pragma unroll
            for (int k = 0; k < 8; ++k) {
                w8 -= vvrow[k] * __shfl(xf_all[7], k * 8 + i);
                y8 += vvrow[k] * rdl(zf_all[7], k * 8);
            }
#pragma unroll
            for (int l = 0; l < 4; ++l) {
                const int ra = 2 * l, rb = 2 * l + 1;
                float p00 = rdl(w8, ra * 9), p01 = rdl(w8, ra * 8 + rb);
                float p10 = rdl(w8, rb * 8 + ra), p11 = rdl(w8, rb * 9);
                float za = rdl(y8, ra * 8), zbv = rdl(y8, rb * 8);
                float rka = __shfl(w8, ra * 8 + i), rkb = __shfl(w8, rb * 8 + i);
                float ma_ = __shfl(w8, g8 + ra), mb_ = __shfl(w8, g8 + rb);
                float di = __builtin_amdgcn_rcpf(p00 * p11 - p01 * p10);
                float i00 = p11 * di, i01 = -p01 * di, i10 = -p10 * di, i11 = p00 * di;
                float sra = i00 * rka + i01 * rkb, srb = i10 * rka + i11 * rkb;
                float sza = i00 * za + i01 * zbv,  szb = i10 * za + i11 * zbv;
                bool pa = (g == ra), pb = (g == rb);
                float wn = w8 - ma_ * sra - mb_ * srb;
                float zn = y8 - ma_ * sza - mb_ * szb;
                w8 = pa ? sra : pb ? srb : wn;
                y8 = pa ? sza : pb ? szb : zn;
            }
            x8c = __shfl(y8, i * 8);           // col-rep
            da = (g == 4) ? x8c : da;
        }
        // ---- P6: dual outward back-substitution (DPP row-sums) ----
        {
            float xcl = x8c, xcu = x8c;
#pragma unroll
            for (int j = 0; j < 8; ++j) {
                {
                    const int t = 7 - j;
                    float p = sum8_dpp(xf_all[t] * xcl);
                    float xr = zf_all[t] + p;
                    float xc = __shfl(xr, i * 8);
                    if (t & 1) db = (g == (t >> 1)) ? xc : db;
                    else       da = (g == (t >> 1)) ? xc : da;
                    xcl = xc;
                }
                if (j < 7) {
                    const int t = 9 + j;
                    float p = sum8_dpp(xb_all[6 - j] * xcu);
                    float xr = zb_all[6 - j] + p;
                    float xc = __shfl(xr, i * 8);
                    if (t & 1) db = (g == (t >> 1)) ? xc : db;
                    else       da = (g == (t >> 1)) ? xc : da;
                    xcu = xc;
                }
            }
        }

        // ---- P7: dz = M^-1 (rhs1 - Am' dnu) ----
        float hxa = rxa - da, hxb = rxb - db;
#pragma unroll
        for (int k = 0; k < 8; ++k) {
            hxa += AcolT[k] * __shfl(db, g8 + k);
            hxb += (g < 7) ? AcolT[k] * __shfl(da, gp1 + k) : 0.f;
        }
        float hur = rur;
#pragma unroll
        for (int k = 0; k < 8; ++k) {
            float va = __shfl(da, g8 + k), vb = __shfl(db, g8 + k);
            hur += BcolU[k] * (isel ? vb : va);
        }
        float dxa = 0.f, dxb = 0.f;
#pragma unroll
        for (int j = 0; j < 8; ++j) {
            dxa += Qirow[j] * __shfl(hxa, g8 + j);
            dxb += Qirow[j] * __shfl(hxb, g8 + j);
        }
        float dur;
        {
            float4 rr = rti4[(2 * g + (isel ? 1 : 0)) * 4 + pu];
            dur = rr.x * __shfl(hur, g8 + isel)
                + rr.y * __shfl(hur, g8 + isel + 1)
                + rr.z * __shfl(hur, g8 + isel + 2)
                + rr.w * __shfl(hur, g8 + isel + 3);
        }

        // ---- P8: ds, dlam, alpha, update ----
        float dss1 = -ri1v - dur;
        float dss2 = -ri2v + dur;
        float dll1 = (-rc1v - l1r * dss1) * is1;
        float dll2 = (-rc2v - l2r * dss2) * is2;
        float rmin = __builtin_inff();
        if (dss1 < 0.f) rmin = fminf(rmin, -s1r * __builtin_amdgcn_rcpf(dss1));
        if (dss2 < 0.f) rmin = fminf(rmin, -s2r * __builtin_amdgcn_rcpf(dss2));
        if (dll1 < 0.f) rmin = fminf(rmin, -l1r * __builtin_amdgcn_rcpf(dll1));
        if (dll2 < 0.f) rmin = fminf(rmin, -l2r * __builtin_amdgcn_rcpf(dll2));
        rmin = wmin64_fast(rmin);
        float alpha = fminf(1.f, 0.99f * rmin);

        ur  += alpha * dur;
        s1r += alpha * dss1; s2r += alpha * dss2;
        l1r += alpha * dll1; l2r += alpha * dll2;
        xa  += alpha * dxa;  xb  += alpha * dxb;
        na  += alpha * da;   nb  += alpha * db;
    }

    out[bi * 128 + 16 * g + i]     = xa;
    out[bi * 128 + 16 * g + 8 + i] = xb;
    out[16384 + bi * 64 + tid]     = ur;
}

extern "C" void kernel_launch(void* const* d_in, const int* in_sizes, int n_in,
                              void* d_out, int out_size, void* d_ws, size_t ws_size,
                              hipStream_t stream) {
    const float* x0 = (const float*)d_in[0];
    const float* fc = (const float*)d_in[1];
    const float* A  = (const float*)d_in[2];
    const float* B  = (const float*)d_in[3];
    const float* C  = (const float*)d_in[4];
    const float* Q  = (const float*)d_in[5];
    const float* R  = (const float*)d_in[6];
    float* out = (float*)d_out;
    const int batch = in_sizes[0] / 8;  // 128
    mpc_ipm_kernel<<<batch, 64, 0, stream>>>(x0, fc, A, B, C, Q, R, out);
}